// Round 1
// baseline (748.241 us; speedup 1.0000x reference)
//
#include <hip/hip_runtime.h>
#include <math.h>

#define N_NODES 100000
#define N_EDGES 1600000
#define D_IN    128
#define HIDDEN  128
#define D_OUT   64

#define SCAN_CHUNK 2048
#define SCAN_NB ((N_NODES + SCAN_CHUNK - 1) / SCAN_CHUNK)   // 49

// ---------------- CSR build ----------------

__global__ void hist_kernel(const int* __restrict__ dst, int* __restrict__ cnt) {
    int i = blockIdx.x * blockDim.x + threadIdx.x;
    int stride = gridDim.x * blockDim.x;
    for (; i < N_EDGES; i += stride)
        atomicAdd(&cnt[dst[i]], 1);
}

__global__ void scan_pass1(const int* __restrict__ cnt, int* __restrict__ blockSum) {
    __shared__ int sdata[256];
    int base = blockIdx.x * SCAN_CHUNK + threadIdx.x * 8;
    int s = 0;
#pragma unroll
    for (int j = 0; j < 8; ++j) {
        int idx = base + j;
        s += (idx < N_NODES) ? cnt[idx] : 0;
    }
    sdata[threadIdx.x] = s;
    __syncthreads();
    for (int off = 128; off > 0; off >>= 1) {
        if (threadIdx.x < off) sdata[threadIdx.x] += sdata[threadIdx.x + off];
        __syncthreads();
    }
    if (threadIdx.x == 0) blockSum[blockIdx.x] = sdata[0];
}

__global__ void scan_pass2(const int* __restrict__ blockSum, int* __restrict__ blockOff,
                           int* __restrict__ rowStart) {
    if (threadIdx.x == 0 && blockIdx.x == 0) {
        int acc = 0;
        for (int b = 0; b < SCAN_NB; ++b) { blockOff[b] = acc; acc += blockSum[b]; }
        rowStart[N_NODES] = acc;   // == N_EDGES
    }
}

__global__ void scan_pass3(const int* __restrict__ cnt, const int* __restrict__ blockOff,
                           int* __restrict__ rowStart) {
    __shared__ int sums[256];
    int t = threadIdx.x;
    int base = blockIdx.x * SCAN_CHUNK + t * 8;
    int v[8];
    int s = 0;
#pragma unroll
    for (int j = 0; j < 8; ++j) {
        int idx = base + j;
        v[j] = (idx < N_NODES) ? cnt[idx] : 0;
        s += v[j];
    }
    sums[t] = s;
    __syncthreads();
    for (int off = 1; off < 256; off <<= 1) {
        int tmp = (t >= off) ? sums[t - off] : 0;
        __syncthreads();
        sums[t] += tmp;
        __syncthreads();
    }
    int running = blockOff[blockIdx.x] + sums[t] - s;   // exclusive prefix
#pragma unroll
    for (int j = 0; j < 8; ++j) {
        int idx = base + j;
        if (idx < N_NODES) rowStart[idx] = running;
        running += v[j];
    }
}

__global__ void fill_kernel(const int* __restrict__ src, const int* __restrict__ dst,
                            int* __restrict__ cursor, int* __restrict__ srcSorted) {
    int i = blockIdx.x * blockDim.x + threadIdx.x;
    int stride = gridDim.x * blockDim.x;
    for (; i < N_EDGES; i += stride) {
        int d = dst[i];
        int pos = atomicAdd(&cursor[d], 1);
        srcSorted[pos] = src[i];
    }
}

// ---------------- Aggregation (gather over CSR) ----------------

// mean1[n][0:128] = mean over incoming src of x[src]; one wave per node, float2/lane
__global__ void agg1_kernel(const float* __restrict__ x, const int* __restrict__ rowStart,
                            const int* __restrict__ srcSorted, float* __restrict__ mean1) {
    int wave = threadIdx.x >> 6;
    int lane = threadIdx.x & 63;
    int node = blockIdx.x * 4 + wave;
    if (node >= N_NODES) return;
    int b = rowStart[node], e = rowStart[node + 1];
    float2 acc = {0.f, 0.f};
    for (int i = b; i < e; ++i) {
        int s = srcSorted[i];
        float2 v = ((const float2*)(x + (size_t)s * 128))[lane];
        acc.x += v.x; acc.y += v.y;
    }
    float inv = 1.0f / (float)max(e - b, 1);
    float2 m; m.x = acc.x * inv; m.y = acc.y * inv;
    ((float2*)(mean1 + (size_t)node * 128))[lane] = m;
}

// out[n][c] = sigmoid( mean_i p[src_i][c] + q[n][c] ); width 64, one wave per node
__global__ void agg2_kernel(const float* __restrict__ p, const float* __restrict__ q,
                            const int* __restrict__ rowStart, const int* __restrict__ srcSorted,
                            float* __restrict__ out) {
    int wave = threadIdx.x >> 6;
    int lane = threadIdx.x & 63;
    int node = blockIdx.x * 4 + wave;
    if (node >= N_NODES) return;
    int b = rowStart[node], e = rowStart[node + 1];
    float acc = 0.f;
    for (int i = b; i < e; ++i) {
        int s = srcSorted[i];
        acc += p[(size_t)s * 64 + lane];
    }
    float inv = 1.0f / (float)max(e - b, 1);
    float z = acc * inv + q[(size_t)node * 64 + lane];
    out[(size_t)node * 64 + lane] = 1.0f / (1.0f + expf(-z));
}

// ---------------- GEMMs (fp32 vector, tiled) ----------------
// Layer 1: h = relu( [mean1|x] @ [Wl1;Wr1] + bl1 ).  M=100000, N=128, K=256.
__global__ __launch_bounds__(256) void gemm1_kernel(
    const float* __restrict__ mean1, const float* __restrict__ x,
    const float* __restrict__ Wl1, const float* __restrict__ Wr1,
    const float* __restrict__ bl1, float* __restrict__ h)
{
    __shared__ float As[16][64];    // [k][m] transposed
    __shared__ float Bs[16][128];
    int tid = threadIdx.x;
    int tx = tid & 15, ty = tid >> 4;
    int blockRow = blockIdx.x * 64;

    float acc[4][8];
#pragma unroll
    for (int r = 0; r < 4; ++r)
#pragma unroll
        for (int c = 0; c < 8; ++c) acc[r][c] = 0.f;

    int am = tid >> 2;          // 0..63 (A tile row)
    int ak = (tid & 3) * 4;     // k offset within chunk: 0,4,8,12
    int bk = tid >> 4;          // 0..15 (B k within chunk)
    int bc = (tid & 15) * 8;    // B col: 0..120

    int arow = blockRow + am;
    for (int kc = 0; kc < 16; ++kc) {
        int kbase = kc * 16;
        // --- stage A (transposed into LDS) ---
        float4 av = {0.f, 0.f, 0.f, 0.f};
        if (arow < N_NODES) {
            const float* Aptr = (kbase < 128)
                ? (mean1 + (size_t)arow * 128 + kbase + ak)
                : (x + (size_t)arow * 128 + (kbase - 128) + ak);
            av = *(const float4*)Aptr;
        }
        As[ak + 0][am] = av.x;
        As[ak + 1][am] = av.y;
        As[ak + 2][am] = av.z;
        As[ak + 3][am] = av.w;
        // --- stage B ---
        int kglob = kbase + bk;
        const float* Bp = (kglob < 128) ? (Wl1 + (size_t)kglob * 128 + bc)
                                        : (Wr1 + (size_t)(kglob - 128) * 128 + bc);
        *(float4*)&Bs[bk][bc]     = *(const float4*)Bp;
        *(float4*)&Bs[bk][bc + 4] = *(const float4*)(Bp + 4);
        __syncthreads();
#pragma unroll
        for (int kk = 0; kk < 16; ++kk) {
            float4 af = *(const float4*)&As[kk][ty * 4];
            float4 b0 = *(const float4*)&Bs[kk][tx * 4];
            float4 b1 = *(const float4*)&Bs[kk][64 + tx * 4];
            float a_[4] = {af.x, af.y, af.z, af.w};
            float b_[8] = {b0.x, b0.y, b0.z, b0.w, b1.x, b1.y, b1.z, b1.w};
#pragma unroll
            for (int r = 0; r < 4; ++r)
#pragma unroll
                for (int c = 0; c < 8; ++c)
                    acc[r][c] += a_[r] * b_[c];
        }
        __syncthreads();
    }

    float4 biasL = *(const float4*)&bl1[tx * 4];
    float4 biasH = *(const float4*)&bl1[64 + tx * 4];
    float bL[4] = {biasL.x, biasL.y, biasL.z, biasL.w};
    float bH[4] = {biasH.x, biasH.y, biasH.z, biasH.w};
#pragma unroll
    for (int r = 0; r < 4; ++r) {
        int row = blockRow + ty * 4 + r;
        if (row < N_NODES) {
            float4 lo, hi;
            lo.x = fmaxf(acc[r][0] + bL[0], 0.f);
            lo.y = fmaxf(acc[r][1] + bL[1], 0.f);
            lo.z = fmaxf(acc[r][2] + bL[2], 0.f);
            lo.w = fmaxf(acc[r][3] + bL[3], 0.f);
            hi.x = fmaxf(acc[r][4] + bH[0], 0.f);
            hi.y = fmaxf(acc[r][5] + bH[1], 0.f);
            hi.z = fmaxf(acc[r][6] + bH[2], 0.f);
            hi.w = fmaxf(acc[r][7] + bH[3], 0.f);
            *(float4*)&h[(size_t)row * 128 + tx * 4]      = lo;
            *(float4*)&h[(size_t)row * 128 + 64 + tx * 4] = hi;
        }
    }
}

// Layer 2 pre-mult: p = h@Wl2 ; q = h@Wr2 + bl2.  M=100000, N=64+64, K=128.
__global__ __launch_bounds__(256) void gemm2_kernel(
    const float* __restrict__ h,
    const float* __restrict__ Wl2, const float* __restrict__ Wr2,
    const float* __restrict__ bl2, float* __restrict__ p, float* __restrict__ q)
{
    __shared__ float As[16][64];
    __shared__ float Bs[16][128];
    int tid = threadIdx.x;
    int tx = tid & 15, ty = tid >> 4;
    int blockRow = blockIdx.x * 64;

    float acc[4][8];
#pragma unroll
    for (int r = 0; r < 4; ++r)
#pragma unroll
        for (int c = 0; c < 8; ++c) acc[r][c] = 0.f;

    int am = tid >> 2;
    int ak = (tid & 3) * 4;
    int bk = tid >> 4;
    int bc = (tid & 15) * 8;

    int arow = blockRow + am;
    for (int kc = 0; kc < 8; ++kc) {
        int kbase = kc * 16;
        float4 av = {0.f, 0.f, 0.f, 0.f};
        if (arow < N_NODES)
            av = *(const float4*)(h + (size_t)arow * 128 + kbase + ak);
        As[ak + 0][am] = av.x;
        As[ak + 1][am] = av.y;
        As[ak + 2][am] = av.z;
        As[ak + 3][am] = av.w;
        int kglob = kbase + bk;
        const float* Bp = (bc < 64) ? (Wl2 + (size_t)kglob * 64 + bc)
                                    : (Wr2 + (size_t)kglob * 64 + (bc - 64));
        *(float4*)&Bs[bk][bc]     = *(const float4*)Bp;
        *(float4*)&Bs[bk][bc + 4] = *(const float4*)(Bp + 4);
        __syncthreads();
#pragma unroll
        for (int kk = 0; kk < 16; ++kk) {
            float4 af = *(const float4*)&As[kk][ty * 4];
            float4 b0 = *(const float4*)&Bs[kk][tx * 4];
            float4 b1 = *(const float4*)&Bs[kk][64 + tx * 4];
            float a_[4] = {af.x, af.y, af.z, af.w};
            float b_[8] = {b0.x, b0.y, b0.z, b0.w, b1.x, b1.y, b1.z, b1.w};
#pragma unroll
            for (int r = 0; r < 4; ++r)
#pragma unroll
                for (int c = 0; c < 8; ++c)
                    acc[r][c] += a_[r] * b_[c];
        }
        __syncthreads();
    }

    float4 bias = *(const float4*)&bl2[tx * 4];
    float bB[4] = {bias.x, bias.y, bias.z, bias.w};
#pragma unroll
    for (int r = 0; r < 4; ++r) {
        int row = blockRow + ty * 4 + r;
        if (row < N_NODES) {
            float4 pv, qv;
            pv.x = acc[r][0]; pv.y = acc[r][1]; pv.z = acc[r][2]; pv.w = acc[r][3];
            qv.x = acc[r][4] + bB[0];
            qv.y = acc[r][5] + bB[1];
            qv.z = acc[r][6] + bB[2];
            qv.w = acc[r][7] + bB[3];
            *(float4*)&p[(size_t)row * 64 + tx * 4] = pv;
            *(float4*)&q[(size_t)row * 64 + tx * 4] = qv;
        }
    }
}

// ---------------- launch ----------------

extern "C" void kernel_launch(void* const* d_in, const int* in_sizes, int n_in,
                              void* d_out, int out_size, void* d_ws, size_t ws_size,
                              hipStream_t stream) {
    const float* x   = (const float*)d_in[0];
    const int*   ei  = (const int*)d_in[1];
    const float* Wl1 = (const float*)d_in[2];
    const float* bl1 = (const float*)d_in[3];
    const float* Wr1 = (const float*)d_in[4];
    const float* Wl2 = (const float*)d_in[5];
    const float* bl2 = (const float*)d_in[6];
    const float* Wr2 = (const float*)d_in[7];
    float* out = (float*)d_out;

    const int* src = ei;
    const int* dst = ei + N_EDGES;

    // workspace carve-up (≈110 MB)
    char* ws = (char*)d_ws;
    size_t off = 0;
    auto carve = [&](size_t bytes) -> void* {
        void* ptr = ws + off;
        off = (off + bytes + 255) & ~(size_t)255;
        return ptr;
    };
    int* rowStart  = (int*)carve((N_NODES + 1) * sizeof(int));
    int* cursor    = (int*)carve(N_NODES * sizeof(int));
    int* blockSum  = (int*)carve(SCAN_NB * sizeof(int));
    int* blockOff  = (int*)carve(SCAN_NB * sizeof(int));
    int* srcSorted = (int*)carve(N_EDGES * sizeof(int));
    float* h       = (float*)carve((size_t)N_NODES * HIDDEN * sizeof(float));
    float* mean1   = (float*)carve((size_t)N_NODES * HIDDEN * sizeof(float));
    float* p       = mean1;                              // reuse: mean1 dead after gemm1
    float* q       = mean1 + (size_t)N_NODES * D_OUT;

    // 1. CSR build
    hipMemsetAsync(cursor, 0, N_NODES * sizeof(int), stream);
    hist_kernel<<<6250, 256, 0, stream>>>(dst, cursor);
    scan_pass1<<<SCAN_NB, 256, 0, stream>>>(cursor, blockSum);
    scan_pass2<<<1, 64, 0, stream>>>(blockSum, blockOff, rowStart);
    scan_pass3<<<SCAN_NB, 256, 0, stream>>>(cursor, blockOff, rowStart);
    hipMemcpyAsync(cursor, rowStart, N_NODES * sizeof(int), hipMemcpyDeviceToDevice, stream);
    fill_kernel<<<6250, 256, 0, stream>>>(src, dst, cursor, srcSorted);

    // 2. layer 1
    agg1_kernel<<<(N_NODES + 3) / 4, 256, 0, stream>>>(x, rowStart, srcSorted, mean1);
    gemm1_kernel<<<(N_NODES + 63) / 64, 256, 0, stream>>>(mean1, x, Wl1, Wr1, bl1, h);

    // 3. layer 2 (pre-multiply then aggregate: mean(h)@Wl2 == mean(h@Wl2))
    gemm2_kernel<<<(N_NODES + 63) / 64, 256, 0, stream>>>(h, Wl2, Wr2, bl2, p, q);
    agg2_kernel<<<(N_NODES + 3) / 4, 256, 0, stream>>>(p, q, rowStart, srcSorted, out);
}

// Round 2
// 498.086 us; speedup vs baseline: 1.5022x; 1.5022x over previous
//
#include <hip/hip_runtime.h>
#include <math.h>

#define N_NODES 100000
#define N_EDGES 1600000
#define D_IN    128
#define HIDDEN  128
#define D_OUT   64

#define SCAN_CHUNK 2048
#define SCAN_NB ((N_NODES + SCAN_CHUNK - 1) / SCAN_CHUNK)   // 49

typedef short bf16x8 __attribute__((ext_vector_type(8)));
typedef float f32x4  __attribute__((ext_vector_type(4)));

__device__ __forceinline__ unsigned short f2bf(float f) {
    union { float f; unsigned u; } v; v.f = f;
    unsigned r = v.u + 0x7FFF + ((v.u >> 16) & 1);   // RNE
    return (unsigned short)(r >> 16);
}
__device__ __forceinline__ float bf2f_lo(unsigned u) {  // low ushort -> float
    union { unsigned u; float f; } v; v.u = u << 16; return v.f;
}
__device__ __forceinline__ float bf2f_hi(unsigned u) {  // high ushort -> float
    union { unsigned u; float f; } v; v.u = u & 0xFFFF0000u; return v.f;
}

// ---------------- CSR build ----------------

__global__ void hist_kernel(const int* __restrict__ dst, int* __restrict__ cnt) {
    int i = blockIdx.x * blockDim.x + threadIdx.x;
    int stride = gridDim.x * blockDim.x;
    for (; i < N_EDGES; i += stride)
        atomicAdd(&cnt[dst[i]], 1);
}

__global__ void scan_pass1(const int* __restrict__ cnt, int* __restrict__ blockSum) {
    __shared__ int sdata[256];
    int base = blockIdx.x * SCAN_CHUNK + threadIdx.x * 8;
    int s = 0;
#pragma unroll
    for (int j = 0; j < 8; ++j) {
        int idx = base + j;
        s += (idx < N_NODES) ? cnt[idx] : 0;
    }
    sdata[threadIdx.x] = s;
    __syncthreads();
    for (int off = 128; off > 0; off >>= 1) {
        if (threadIdx.x < off) sdata[threadIdx.x] += sdata[threadIdx.x + off];
        __syncthreads();
    }
    if (threadIdx.x == 0) blockSum[blockIdx.x] = sdata[0];
}

__global__ void scan_pass2(const int* __restrict__ blockSum, int* __restrict__ blockOff,
                           int* __restrict__ rowStart) {
    if (threadIdx.x == 0 && blockIdx.x == 0) {
        int acc = 0;
        for (int b = 0; b < SCAN_NB; ++b) { blockOff[b] = acc; acc += blockSum[b]; }
        rowStart[N_NODES] = acc;
    }
}

__global__ void scan_pass3(const int* __restrict__ cnt, const int* __restrict__ blockOff,
                           int* __restrict__ rowStart) {
    __shared__ int sums[256];
    int t = threadIdx.x;
    int base = blockIdx.x * SCAN_CHUNK + t * 8;
    int v[8];
    int s = 0;
#pragma unroll
    for (int j = 0; j < 8; ++j) {
        int idx = base + j;
        v[j] = (idx < N_NODES) ? cnt[idx] : 0;
        s += v[j];
    }
    sums[t] = s;
    __syncthreads();
    for (int off = 1; off < 256; off <<= 1) {
        int tmp = (t >= off) ? sums[t - off] : 0;
        __syncthreads();
        sums[t] += tmp;
        __syncthreads();
    }
    int running = blockOff[blockIdx.x] + sums[t] - s;
#pragma unroll
    for (int j = 0; j < 8; ++j) {
        int idx = base + j;
        if (idx < N_NODES) rowStart[idx] = running;
        running += v[j];
    }
}

__global__ void fill_kernel(const int* __restrict__ src, const int* __restrict__ dst,
                            int* __restrict__ cursor, int* __restrict__ srcSorted) {
    int i = blockIdx.x * blockDim.x + threadIdx.x;
    int stride = gridDim.x * blockDim.x;
    for (; i < N_EDGES; i += stride) {
        int d = dst[i];
        int pos = atomicAdd(&cursor[d], 1);
        srcSorted[pos] = src[i];
    }
}

// ---------------- dtype prep ----------------

// x (fp32, N x 128) -> xb (bf16 packed pairs, N x 64 uints)
__global__ void convert_x_kernel(const float* __restrict__ x, unsigned* __restrict__ xb) {
    long long t = (long long)blockIdx.x * blockDim.x + threadIdx.x;   // one per 4 floats
    if (t >= (long long)N_NODES * 32) return;
    float4 v = ((const float4*)x)[t];
    unsigned u0 = (unsigned)f2bf(v.x) | ((unsigned)f2bf(v.y) << 16);
    unsigned u1 = (unsigned)f2bf(v.z) | ((unsigned)f2bf(v.w) << 16);
    ((uint2*)xb)[t] = make_uint2(u0, u1);
}

// Pre-arrange B matrices into MFMA fragment order (bf16).
// Fragment slot for element B[k][n]:
//   kstep=k>>5, quad=(k>>3)&3, j=k&7, ntile=n>>4, lane=quad*16+(n&15)
//   short index = ((kstep*8 + ntile)*64 + lane)*8 + j
__global__ void prep_b_kernel(const float* __restrict__ Wl1, const float* __restrict__ Wr1,
                              const float* __restrict__ Wl2, const float* __restrict__ Wr2,
                              unsigned short* __restrict__ B1, unsigned short* __restrict__ B2) {
    int e = blockIdx.x * blockDim.x + threadIdx.x;
    if (e < 256 * 128) {   // B1 = [Wl1; Wr1], 256 x 128
        int k = e >> 7, n = e & 127;
        float w = (k < 128) ? Wl1[k * 128 + n] : Wr1[(k - 128) * 128 + n];
        int kstep = k >> 5, quad = (k >> 3) & 3, j = k & 7;
        int lane = quad * 16 + (n & 15), ntile = n >> 4;
        B1[((kstep * 8 + ntile) * 64 + lane) * 8 + j] = f2bf(w);
    } else {               // B2 = [Wl2 | Wr2], 128 x 128 (cols 0-63 p, 64-127 q)
        int e2 = e - 256 * 128;
        if (e2 >= 128 * 128) return;
        int k = e2 >> 7, n = e2 & 127;
        float w = (n < 64) ? Wl2[k * 64 + n] : Wr2[k * 64 + (n - 64)];
        int kstep = k >> 5, quad = (k >> 3) & 3, j = k & 7;
        int lane = quad * 16 + (n & 15), ntile = n >> 4;
        B2[((kstep * 8 + ntile) * 64 + lane) * 8 + j] = f2bf(w);
    }
}

// ---------------- Aggregation ----------------

// meanb[n] = mean of xb[src] rows (bf16 in, fp32 acc, bf16 out). One wave per node.
__global__ void agg1_kernel(const unsigned* __restrict__ xb, const int* __restrict__ rowStart,
                            const int* __restrict__ srcSorted, unsigned* __restrict__ meanb) {
    int wave = threadIdx.x >> 6;
    int lane = threadIdx.x & 63;
    int node = blockIdx.x * 4 + wave;
    if (node >= N_NODES) return;
    int b = rowStart[node], e = rowStart[node + 1];
    float ax = 0.f, ay = 0.f;
    int i = b;
    for (; i + 4 <= e; i += 4) {
        int s0 = srcSorted[i], s1 = srcSorted[i + 1], s2 = srcSorted[i + 2], s3 = srcSorted[i + 3];
        unsigned u0 = xb[(size_t)s0 * 64 + lane];
        unsigned u1 = xb[(size_t)s1 * 64 + lane];
        unsigned u2 = xb[(size_t)s2 * 64 + lane];
        unsigned u3 = xb[(size_t)s3 * 64 + lane];
        ax += bf2f_lo(u0) + bf2f_lo(u1) + bf2f_lo(u2) + bf2f_lo(u3);
        ay += bf2f_hi(u0) + bf2f_hi(u1) + bf2f_hi(u2) + bf2f_hi(u3);
    }
    for (; i < e; ++i) {
        unsigned u = xb[(size_t)srcSorted[i] * 64 + lane];
        ax += bf2f_lo(u); ay += bf2f_hi(u);
    }
    float inv = 1.0f / (float)max(e - b, 1);
    meanb[(size_t)node * 64 + lane] =
        (unsigned)f2bf(ax * inv) | ((unsigned)f2bf(ay * inv) << 16);
}

// out[n][c] = sigmoid( mean_i p[src_i][c] + q[n][c] ), p bf16, q fp32.
__global__ void agg2_kernel(const unsigned short* __restrict__ p, const float* __restrict__ q,
                            const int* __restrict__ rowStart, const int* __restrict__ srcSorted,
                            float* __restrict__ out) {
    int wave = threadIdx.x >> 6;
    int lane = threadIdx.x & 63;
    int node = blockIdx.x * 4 + wave;
    if (node >= N_NODES) return;
    int b = rowStart[node], e = rowStart[node + 1];
    float acc = 0.f;
    int i = b;
    for (; i + 4 <= e; i += 4) {
        int s0 = srcSorted[i], s1 = srcSorted[i + 1], s2 = srcSorted[i + 2], s3 = srcSorted[i + 3];
        float v0 = bf2f_lo((unsigned)p[(size_t)s0 * 64 + lane]);
        float v1 = bf2f_lo((unsigned)p[(size_t)s1 * 64 + lane]);
        float v2 = bf2f_lo((unsigned)p[(size_t)s2 * 64 + lane]);
        float v3 = bf2f_lo((unsigned)p[(size_t)s3 * 64 + lane]);
        acc += v0 + v1 + v2 + v3;
    }
    for (; i < e; ++i)
        acc += bf2f_lo((unsigned)p[(size_t)srcSorted[i] * 64 + lane]);
    float inv = 1.0f / (float)max(e - b, 1);
    float z = acc * inv + q[(size_t)node * 64 + lane];
    out[(size_t)node * 64 + lane] = 1.0f / (1.0f + __expf(-z));
}

// ---------------- MFMA GEMMs ----------------
// gemm1: h = relu([meanb | xb] @ B1 + bl1), M=100000 N=128 K=256, h bf16.
// Block = 256 thr (4 waves), 64 rows/block, B1 fragments staged in LDS (64 KB).
__global__ __launch_bounds__(256) void gemm1_kernel(
    const unsigned short* __restrict__ meanb, const unsigned short* __restrict__ xb,
    const unsigned short* __restrict__ B1, const float* __restrict__ bl1,
    unsigned short* __restrict__ h)
{
    __shared__ int ldsB[16384];   // 64 KB: 8 ksteps x 8 ntiles x 64 lanes x 16 B
    int tid = threadIdx.x;
    for (int i = tid; i < 4096; i += 256)
        ((int4*)ldsB)[i] = ((const int4*)B1)[i];
    __syncthreads();

    int lane = tid & 63;
    int waveId = tid >> 6;
    int m = lane & 15, quad = lane >> 4;
    int rowBase = blockIdx.x * 64 + waveId * 16;
    int arow = rowBase + m;
    bool rowOk = arow < N_NODES;

    f32x4 acc[8];
#pragma unroll
    for (int t = 0; t < 8; ++t) acc[t] = (f32x4){0.f, 0.f, 0.f, 0.f};

    const bf16x8* lds = (const bf16x8*)ldsB;
#pragma unroll
    for (int kstep = 0; kstep < 8; ++kstep) {
        int kglob = kstep * 32 + quad * 8;
        bf16x8 afrag = (bf16x8)(short)0;
        if (rowOk) {
            const unsigned short* ap = (kglob < 128)
                ? (meanb + (size_t)arow * 128 + kglob)
                : (xb + (size_t)arow * 128 + (kglob - 128));
            afrag = *(const bf16x8*)ap;
        }
#pragma unroll
        for (int nt = 0; nt < 8; ++nt) {
            bf16x8 bfrag = lds[(kstep * 8 + nt) * 64 + lane];
            acc[nt] = __builtin_amdgcn_mfma_f32_16x16x32_bf16(afrag, bfrag, acc[nt], 0, 0, 0);
        }
    }

#pragma unroll
    for (int nt = 0; nt < 8; ++nt) {
        int col = nt * 16 + m;
        float bias = bl1[col];
#pragma unroll
        for (int r = 0; r < 4; ++r) {
            int row = rowBase + quad * 4 + r;
            if (row < N_NODES) {
                float v = fmaxf(acc[nt][r] + bias, 0.f);
                h[(size_t)row * 128 + col] = f2bf(v);
            }
        }
    }
}

// gemm2: [p | q] = h @ B2 (+bl2 on q half), M=100000 N=128 K=128. p bf16, q fp32.
__global__ __launch_bounds__(256) void gemm2_kernel(
    const unsigned short* __restrict__ h, const unsigned short* __restrict__ B2,
    const float* __restrict__ bl2,
    unsigned short* __restrict__ p, float* __restrict__ q)
{
    __shared__ int ldsB[8192];    // 32 KB: 4 ksteps x 8 ntiles x 64 x 16 B
    int tid = threadIdx.x;
    for (int i = tid; i < 2048; i += 256)
        ((int4*)ldsB)[i] = ((const int4*)B2)[i];
    __syncthreads();

    int lane = tid & 63;
    int waveId = tid >> 6;
    int m = lane & 15, quad = lane >> 4;
    int rowBase = blockIdx.x * 64 + waveId * 16;
    int arow = rowBase + m;
    bool rowOk = arow < N_NODES;

    f32x4 acc[8];
#pragma unroll
    for (int t = 0; t < 8; ++t) acc[t] = (f32x4){0.f, 0.f, 0.f, 0.f};

    const bf16x8* lds = (const bf16x8*)ldsB;
#pragma unroll
    for (int kstep = 0; kstep < 4; ++kstep) {
        int kglob = kstep * 32 + quad * 8;
        bf16x8 afrag = (bf16x8)(short)0;
        if (rowOk)
            afrag = *(const bf16x8*)(h + (size_t)arow * 128 + kglob);
#pragma unroll
        for (int nt = 0; nt < 8; ++nt) {
            bf16x8 bfrag = lds[(kstep * 8 + nt) * 64 + lane];
            acc[nt] = __builtin_amdgcn_mfma_f32_16x16x32_bf16(afrag, bfrag, acc[nt], 0, 0, 0);
        }
    }

#pragma unroll
    for (int nt = 0; nt < 8; ++nt) {
        int col = nt * 16 + m;
        float bias = (col >= 64) ? bl2[col - 64] : 0.f;
#pragma unroll
        for (int r = 0; r < 4; ++r) {
            int row = rowBase + quad * 4 + r;
            if (row < N_NODES) {
                float v = acc[nt][r];
                if (col < 64)
                    p[(size_t)row * 64 + col] = f2bf(v);
                else
                    q[(size_t)row * 64 + (col - 64)] = v + bias;
            }
        }
    }
}

// ---------------- launch ----------------

extern "C" void kernel_launch(void* const* d_in, const int* in_sizes, int n_in,
                              void* d_out, int out_size, void* d_ws, size_t ws_size,
                              hipStream_t stream) {
    const float* x   = (const float*)d_in[0];
    const int*   ei  = (const int*)d_in[1];
    const float* Wl1 = (const float*)d_in[2];
    const float* bl1 = (const float*)d_in[3];
    const float* Wr1 = (const float*)d_in[4];
    const float* Wl2 = (const float*)d_in[5];
    const float* bl2 = (const float*)d_in[6];
    const float* Wr2 = (const float*)d_in[7];
    float* out = (float*)d_out;

    const int* src = ei;
    const int* dst = ei + N_EDGES;

    char* ws = (char*)d_ws;
    size_t off = 0;
    auto carve = [&](size_t bytes) -> void* {
        void* ptr = ws + off;
        off = (off + bytes + 255) & ~(size_t)255;
        return ptr;
    };
    int* rowStart  = (int*)carve((N_NODES + 1) * sizeof(int));
    int* cursor    = (int*)carve(N_NODES * sizeof(int));
    int* blockSum  = (int*)carve(SCAN_NB * sizeof(int));
    int* blockOff  = (int*)carve(SCAN_NB * sizeof(int));
    int* srcSorted = (int*)carve(N_EDGES * sizeof(int));
    unsigned* xb   = (unsigned*)carve((size_t)N_NODES * 64 * sizeof(unsigned));        // 25.6 MB (bf16 x)
    unsigned* meanb= (unsigned*)carve((size_t)N_NODES * 64 * sizeof(unsigned));        // 25.6 MB
    unsigned short* h = (unsigned short*)carve((size_t)N_NODES * 128 * sizeof(short)); // 25.6 MB
    unsigned short* B1 = (unsigned short*)carve(256 * 128 * sizeof(short));
    unsigned short* B2 = (unsigned short*)carve(128 * 128 * sizeof(short));
    // overlays (producers dead before writes):
    unsigned short* p = (unsigned short*)meanb;   // 12.8 MB into meanb (dead after gemm1)
    float* q = (float*)xb;                        // 25.6 MB into xb   (dead after gemm1)

    // 1. CSR build
    hipMemsetAsync(cursor, 0, N_NODES * sizeof(int), stream);
    hist_kernel<<<6250, 256, 0, stream>>>(dst, cursor);
    scan_pass1<<<SCAN_NB, 256, 0, stream>>>(cursor, blockSum);
    scan_pass2<<<1, 64, 0, stream>>>(blockSum, blockOff, rowStart);
    scan_pass3<<<SCAN_NB, 256, 0, stream>>>(cursor, blockOff, rowStart);
    hipMemcpyAsync(cursor, rowStart, N_NODES * sizeof(int), hipMemcpyDeviceToDevice, stream);
    fill_kernel<<<6250, 256, 0, stream>>>(src, dst, cursor, srcSorted);

    // 2. dtype prep
    convert_x_kernel<<<(N_NODES * 32 + 255) / 256, 256, 0, stream>>>(x, xb);
    prep_b_kernel<<<(256 * 128 + 128 * 128 + 255) / 256, 256, 0, stream>>>(
        Wl1, Wr1, Wl2, Wr2, B1, B2);

    // 3. layer 1
    agg1_kernel<<<(N_NODES + 3) / 4, 256, 0, stream>>>(xb, rowStart, srcSorted, meanb);
    gemm1_kernel<<<(N_NODES + 63) / 64, 256, 0, stream>>>(
        (const unsigned short*)meanb, (const unsigned short*)xb, B1, bl1, h);

    // 4. layer 2 (premultiply then aggregate)
    gemm2_kernel<<<(N_NODES + 63) / 64, 256, 0, stream>>>(h, B2, bl2, p, q);
    agg2_kernel<<<(N_NODES + 3) / 4, 256, 0, stream>>>(p, q, rowStart, srcSorted, out);
}

// Round 3
// 355.812 us; speedup vs baseline: 2.1029x; 1.3999x over previous
//
#include <hip/hip_runtime.h>
#include <math.h>

#define N_NODES 100000
#define N_EDGES 1600000
#define D_IN    128
#define HIDDEN  128
#define D_OUT   64

// ---- bucketed counting sort params ----
#define BUCKET_SHIFT 8                    // 256 nodes per bucket
#define NB_BUCKETS ((N_NODES + 255) / 256)   // 391
#define BUCKET_CAP 6144                   // mean 4096, huge slack
#define EPT 32
#define EPB (256 * EPT)                   // 8192 edges per block
#define NBLK_A ((N_EDGES + EPB - 1) / EPB)   // 196

typedef short bf16x8 __attribute__((ext_vector_type(8)));
typedef float f32x4  __attribute__((ext_vector_type(4)));

__device__ __forceinline__ unsigned short f2bf(float f) {
    union { float f; unsigned u; } v; v.f = f;
    unsigned r = v.u + 0x7FFF + ((v.u >> 16) & 1);   // RNE
    return (unsigned short)(r >> 16);
}
__device__ __forceinline__ float bf2f_lo(unsigned u) {
    union { unsigned u; float f; } v; v.u = u << 16; return v.f;
}
__device__ __forceinline__ float bf2f_hi(unsigned u) {
    union { unsigned u; float f; } v; v.u = u & 0xFFFF0000u; return v.f;
}

// ---------------- CSR build: bucketed counting sort ----------------

// Pass A: scatter edges into per-bucket append regions.
// Entry packs (dstLocal << 17) | src  (src < 2^17, dstLocal < 256).
__global__ __launch_bounds__(256) void bucket_scatter(
    const int* __restrict__ src, const int* __restrict__ dst,
    int* __restrict__ bucketCursor, unsigned* __restrict__ bucketData)
{
    __shared__ int cnt[NB_BUCKETS];
    __shared__ int base[NB_BUCKETS];
    int t = threadIdx.x;
    for (int i = t; i < NB_BUCKETS; i += 256) cnt[i] = 0;
    __syncthreads();
    int start = blockIdx.x * EPB;
    // pass 1: per-block histogram
#pragma unroll 4
    for (int j = 0; j < EPT; ++j) {
        int i = start + j * 256 + t;
        if (i < N_EDGES) atomicAdd(&cnt[dst[i] >> BUCKET_SHIFT], 1);
    }
    __syncthreads();
    // reserve contiguous runs: one global atomic per (block,bucket)
    for (int i = t; i < NB_BUCKETS; i += 256) {
        int c = cnt[i];
        base[i] = (c > 0) ? atomicAdd(&bucketCursor[i], c) : 0;
        cnt[i] = 0;                       // reuse as local rank cursor
    }
    __syncthreads();
    // pass 2: place
#pragma unroll 4
    for (int j = 0; j < EPT; ++j) {
        int i = start + j * 256 + t;
        if (i < N_EDGES) {
            int d = dst[i];
            int b = d >> BUCKET_SHIFT;
            int r = atomicAdd(&cnt[b], 1);
            int pos = base[b] + r;
            if (pos < BUCKET_CAP)
                bucketData[(size_t)b * BUCKET_CAP + pos] =
                    ((unsigned)(d & 255) << 17) | (unsigned)src[i];
        }
    }
}

// Exclusive scan over bucket totals (single block, 512 threads).
__global__ void bucket_scan(const int* __restrict__ bucketCursor,
                            int* __restrict__ bucketStart, int* __restrict__ rowStart)
{
    __shared__ int s[512];
    int t = threadIdx.x;
    int v = (t < NB_BUCKETS) ? bucketCursor[t] : 0;
    s[t] = v;
    __syncthreads();
    for (int off = 1; off < 512; off <<= 1) {
        int tmp = (t >= off) ? s[t - off] : 0;
        __syncthreads();
        s[t] += tmp;
        __syncthreads();
    }
    if (t < NB_BUCKETS) bucketStart[t] = s[t] - v;   // exclusive
    if (t == 511) rowStart[N_NODES] = s[511];        // == N_EDGES
}

// Pass B: one block per bucket -> rowStart + srcSorted (dense contiguous writes).
__global__ __launch_bounds__(256) void bucket_to_csr(
    const unsigned* __restrict__ bucketData, const int* __restrict__ bucketCursor,
    const int* __restrict__ bucketStart,
    int* __restrict__ rowStart, int* __restrict__ srcSorted)
{
    __shared__ unsigned ent[BUCKET_CAP];
    __shared__ int hcnt[256];
    __shared__ int excl[256];
    __shared__ int ss[256];
    int b = blockIdx.x;
    int t = threadIdx.x;
    int n = bucketCursor[b];
    if (n > BUCKET_CAP) n = BUCKET_CAP;
    int gbase = bucketStart[b];
    hcnt[t] = 0;
    __syncthreads();
    for (int i = t; i < n; i += 256) {
        unsigned v = bucketData[(size_t)b * BUCKET_CAP + i];
        ent[i] = v;
        atomicAdd(&hcnt[v >> 17], 1);
    }
    __syncthreads();
    int myc = hcnt[t];
    ss[t] = myc;
    __syncthreads();
    for (int off = 1; off < 256; off <<= 1) {
        int tmp = (t >= off) ? ss[t - off] : 0;
        __syncthreads();
        ss[t] += tmp;
        __syncthreads();
    }
    excl[t] = ss[t] - myc;
    int node = b * 256 + t;
    if (node < N_NODES) rowStart[node] = gbase + excl[t];
    hcnt[t] = 0;                          // reuse as per-node rank cursor
    __syncthreads();
    for (int i = t; i < n; i += 256) {
        unsigned v = ent[i];
        int d = v >> 17;
        int r = atomicAdd(&hcnt[d], 1);
        srcSorted[gbase + excl[d] + r] = (int)(v & 0x1FFFF);
    }
}

// ---------------- dtype prep ----------------

__global__ void convert_x_kernel(const float* __restrict__ x, unsigned* __restrict__ xb) {
    long long t = (long long)blockIdx.x * blockDim.x + threadIdx.x;
    if (t >= (long long)N_NODES * 32) return;
    float4 v = ((const float4*)x)[t];
    unsigned u0 = (unsigned)f2bf(v.x) | ((unsigned)f2bf(v.y) << 16);
    unsigned u1 = (unsigned)f2bf(v.z) | ((unsigned)f2bf(v.w) << 16);
    ((uint2*)xb)[t] = make_uint2(u0, u1);
}

// B matrices -> MFMA fragment order (bf16).
__global__ void prep_b_kernel(const float* __restrict__ Wl1, const float* __restrict__ Wr1,
                              const float* __restrict__ Wl2, const float* __restrict__ Wr2,
                              unsigned short* __restrict__ B1, unsigned short* __restrict__ B2) {
    int e = blockIdx.x * blockDim.x + threadIdx.x;
    if (e < 256 * 128) {
        int k = e >> 7, n = e & 127;
        float w = (k < 128) ? Wl1[k * 128 + n] : Wr1[(k - 128) * 128 + n];
        int kstep = k >> 5, quad = (k >> 3) & 3, j = k & 7;
        int lane = quad * 16 + (n & 15), ntile = n >> 4;
        B1[((kstep * 8 + ntile) * 64 + lane) * 8 + j] = f2bf(w);
    } else {
        int e2 = e - 256 * 128;
        if (e2 >= 128 * 128) return;
        int k = e2 >> 7, n = e2 & 127;
        float w = (n < 64) ? Wl2[k * 64 + n] : Wr2[k * 64 + (n - 64)];
        int kstep = k >> 5, quad = (k >> 3) & 3, j = k & 7;
        int lane = quad * 16 + (n & 15), ntile = n >> 4;
        B2[((kstep * 8 + ntile) * 64 + lane) * 8 + j] = f2bf(w);
    }
}

// ---------------- Aggregation ----------------

__global__ void agg1_kernel(const unsigned* __restrict__ xb, const int* __restrict__ rowStart,
                            const int* __restrict__ srcSorted, unsigned* __restrict__ meanb) {
    int wave = threadIdx.x >> 6;
    int lane = threadIdx.x & 63;
    int node = blockIdx.x * 4 + wave;
    if (node >= N_NODES) return;
    int b = rowStart[node], e = rowStart[node + 1];
    float ax = 0.f, ay = 0.f;
    int i = b;
    for (; i + 4 <= e; i += 4) {
        int s0 = srcSorted[i], s1 = srcSorted[i + 1], s2 = srcSorted[i + 2], s3 = srcSorted[i + 3];
        unsigned u0 = xb[(size_t)s0 * 64 + lane];
        unsigned u1 = xb[(size_t)s1 * 64 + lane];
        unsigned u2 = xb[(size_t)s2 * 64 + lane];
        unsigned u3 = xb[(size_t)s3 * 64 + lane];
        ax += bf2f_lo(u0) + bf2f_lo(u1) + bf2f_lo(u2) + bf2f_lo(u3);
        ay += bf2f_hi(u0) + bf2f_hi(u1) + bf2f_hi(u2) + bf2f_hi(u3);
    }
    for (; i < e; ++i) {
        unsigned u = xb[(size_t)srcSorted[i] * 64 + lane];
        ax += bf2f_lo(u); ay += bf2f_hi(u);
    }
    float inv = 1.0f / (float)max(e - b, 1);
    meanb[(size_t)node * 64 + lane] =
        (unsigned)f2bf(ax * inv) | ((unsigned)f2bf(ay * inv) << 16);
}

__global__ void agg2_kernel(const unsigned short* __restrict__ p, const float* __restrict__ q,
                            const int* __restrict__ rowStart, const int* __restrict__ srcSorted,
                            float* __restrict__ out) {
    int wave = threadIdx.x >> 6;
    int lane = threadIdx.x & 63;
    int node = blockIdx.x * 4 + wave;
    if (node >= N_NODES) return;
    int b = rowStart[node], e = rowStart[node + 1];
    float acc = 0.f;
    int i = b;
    for (; i + 4 <= e; i += 4) {
        int s0 = srcSorted[i], s1 = srcSorted[i + 1], s2 = srcSorted[i + 2], s3 = srcSorted[i + 3];
        float v0 = bf2f_lo((unsigned)p[(size_t)s0 * 64 + lane]);
        float v1 = bf2f_lo((unsigned)p[(size_t)s1 * 64 + lane]);
        float v2 = bf2f_lo((unsigned)p[(size_t)s2 * 64 + lane]);
        float v3 = bf2f_lo((unsigned)p[(size_t)s3 * 64 + lane]);
        acc += v0 + v1 + v2 + v3;
    }
    for (; i < e; ++i)
        acc += bf2f_lo((unsigned)p[(size_t)srcSorted[i] * 64 + lane]);
    float inv = 1.0f / (float)max(e - b, 1);
    float z = acc * inv + q[(size_t)node * 64 + lane];
    out[(size_t)node * 64 + lane] = 1.0f / (1.0f + __expf(-z));
}

// ---------------- MFMA GEMMs ----------------

__global__ __launch_bounds__(256) void gemm1_kernel(
    const unsigned short* __restrict__ meanb, const unsigned short* __restrict__ xb,
    const unsigned short* __restrict__ B1, const float* __restrict__ bl1,
    unsigned short* __restrict__ h)
{
    __shared__ int ldsB[16384];
    int tid = threadIdx.x;
    for (int i = tid; i < 4096; i += 256)
        ((int4*)ldsB)[i] = ((const int4*)B1)[i];
    __syncthreads();

    int lane = tid & 63;
    int waveId = tid >> 6;
    int m = lane & 15, quad = lane >> 4;
    int rowBase = blockIdx.x * 64 + waveId * 16;
    int arow = rowBase + m;
    bool rowOk = arow < N_NODES;

    f32x4 acc[8];
#pragma unroll
    for (int t = 0; t < 8; ++t) acc[t] = (f32x4){0.f, 0.f, 0.f, 0.f};

    const bf16x8* lds = (const bf16x8*)ldsB;
#pragma unroll
    for (int kstep = 0; kstep < 8; ++kstep) {
        int kglob = kstep * 32 + quad * 8;
        bf16x8 afrag = (bf16x8)(short)0;
        if (rowOk) {
            const unsigned short* ap = (kglob < 128)
                ? (meanb + (size_t)arow * 128 + kglob)
                : (xb + (size_t)arow * 128 + (kglob - 128));
            afrag = *(const bf16x8*)ap;
        }
#pragma unroll
        for (int nt = 0; nt < 8; ++nt) {
            bf16x8 bfrag = lds[(kstep * 8 + nt) * 64 + lane];
            acc[nt] = __builtin_amdgcn_mfma_f32_16x16x32_bf16(afrag, bfrag, acc[nt], 0, 0, 0);
        }
    }

#pragma unroll
    for (int nt = 0; nt < 8; ++nt) {
        int col = nt * 16 + m;
        float bias = bl1[col];
#pragma unroll
        for (int r = 0; r < 4; ++r) {
            int row = rowBase + quad * 4 + r;
            if (row < N_NODES) {
                float v = fmaxf(acc[nt][r] + bias, 0.f);
                h[(size_t)row * 128 + col] = f2bf(v);
            }
        }
    }
}

__global__ __launch_bounds__(256) void gemm2_kernel(
    const unsigned short* __restrict__ h, const unsigned short* __restrict__ B2,
    const float* __restrict__ bl2,
    unsigned short* __restrict__ p, float* __restrict__ q)
{
    __shared__ int ldsB[8192];
    int tid = threadIdx.x;
    for (int i = tid; i < 2048; i += 256)
        ((int4*)ldsB)[i] = ((const int4*)B2)[i];
    __syncthreads();

    int lane = tid & 63;
    int waveId = tid >> 6;
    int m = lane & 15, quad = lane >> 4;
    int rowBase = blockIdx.x * 64 + waveId * 16;
    int arow = rowBase + m;
    bool rowOk = arow < N_NODES;

    f32x4 acc[8];
#pragma unroll
    for (int t = 0; t < 8; ++t) acc[t] = (f32x4){0.f, 0.f, 0.f, 0.f};

    const bf16x8* lds = (const bf16x8*)ldsB;
#pragma unroll
    for (int kstep = 0; kstep < 4; ++kstep) {
        int kglob = kstep * 32 + quad * 8;
        bf16x8 afrag = (bf16x8)(short)0;
        if (rowOk)
            afrag = *(const bf16x8*)(h + (size_t)arow * 128 + kglob);
#pragma unroll
        for (int nt = 0; nt < 8; ++nt) {
            bf16x8 bfrag = lds[(kstep * 8 + nt) * 64 + lane];
            acc[nt] = __builtin_amdgcn_mfma_f32_16x16x32_bf16(afrag, bfrag, acc[nt], 0, 0, 0);
        }
    }

#pragma unroll
    for (int nt = 0; nt < 8; ++nt) {
        int col = nt * 16 + m;
        float bias = (col >= 64) ? bl2[col - 64] : 0.f;
#pragma unroll
        for (int r = 0; r < 4; ++r) {
            int row = rowBase + quad * 4 + r;
            if (row < N_NODES) {
                float v = acc[nt][r];
                if (col < 64)
                    p[(size_t)row * 64 + col] = f2bf(v);
                else
                    q[(size_t)row * 64 + (col - 64)] = v + bias;
            }
        }
    }
}

// ---------------- launch ----------------

extern "C" void kernel_launch(void* const* d_in, const int* in_sizes, int n_in,
                              void* d_out, int out_size, void* d_ws, size_t ws_size,
                              hipStream_t stream) {
    const float* x   = (const float*)d_in[0];
    const int*   ei  = (const int*)d_in[1];
    const float* Wl1 = (const float*)d_in[2];
    const float* bl1 = (const float*)d_in[3];
    const float* Wr1 = (const float*)d_in[4];
    const float* Wl2 = (const float*)d_in[5];
    const float* bl2 = (const float*)d_in[6];
    const float* Wr2 = (const float*)d_in[7];
    float* out = (float*)d_out;

    const int* src = ei;
    const int* dst = ei + N_EDGES;

    char* ws = (char*)d_ws;
    size_t off = 0;
    auto carve = [&](size_t bytes) -> void* {
        void* ptr = ws + off;
        off = (off + bytes + 255) & ~(size_t)255;
        return ptr;
    };
    int* rowStart     = (int*)carve((N_NODES + 1) * sizeof(int));
    int* bucketCursor = (int*)carve(NB_BUCKETS * sizeof(int));
    int* bucketStart  = (int*)carve(NB_BUCKETS * sizeof(int));
    unsigned* bucketData = (unsigned*)carve((size_t)NB_BUCKETS * BUCKET_CAP * sizeof(unsigned)); // 9.6 MB
    int* srcSorted    = (int*)carve(N_EDGES * sizeof(int));
    unsigned* xb      = (unsigned*)carve((size_t)N_NODES * 64 * sizeof(unsigned));
    unsigned* meanb   = (unsigned*)carve((size_t)N_NODES * 64 * sizeof(unsigned));
    unsigned short* h = (unsigned short*)carve((size_t)N_NODES * 128 * sizeof(short));
    unsigned short* B1 = (unsigned short*)carve(256 * 128 * sizeof(short));
    unsigned short* B2 = (unsigned short*)carve(128 * 128 * sizeof(short));
    unsigned short* p = (unsigned short*)meanb;   // overlay: meanb dead after gemm1
    float* q = (float*)xb;                        // overlay: xb dead after gemm1

    // 1. CSR build (bucketed counting sort)
    hipMemsetAsync(bucketCursor, 0, NB_BUCKETS * sizeof(int), stream);
    bucket_scatter<<<NBLK_A, 256, 0, stream>>>(src, dst, bucketCursor, bucketData);
    bucket_scan<<<1, 512, 0, stream>>>(bucketCursor, bucketStart, rowStart);
    bucket_to_csr<<<NB_BUCKETS, 256, 0, stream>>>(bucketData, bucketCursor, bucketStart,
                                                  rowStart, srcSorted);

    // 2. dtype prep
    convert_x_kernel<<<(N_NODES * 32 + 255) / 256, 256, 0, stream>>>(x, xb);
    prep_b_kernel<<<(256 * 128 + 128 * 128 + 255) / 256, 256, 0, stream>>>(
        Wl1, Wr1, Wl2, Wr2, B1, B2);

    // 3. layer 1
    agg1_kernel<<<(N_NODES + 3) / 4, 256, 0, stream>>>(xb, rowStart, srcSorted, meanb);
    gemm1_kernel<<<(N_NODES + 63) / 64, 256, 0, stream>>>(
        (const unsigned short*)meanb, (const unsigned short*)xb, B1, bl1, h);

    // 4. layer 2 (premultiply then aggregate)
    gemm2_kernel<<<(N_NODES + 63) / 64, 256, 0, stream>>>(h, B2, bl2, p, q);
    agg2_kernel<<<(N_NODES + 3) / 4, 256, 0, stream>>>(p, q, rowStart, srcSorted, out);
}

// Round 4
// 351.587 us; speedup vs baseline: 2.1282x; 1.0120x over previous
//
#include <hip/hip_runtime.h>
#include <math.h>

#define N_NODES 100000
#define N_EDGES 1600000
#define D_IN    128
#define HIDDEN  128
#define D_OUT   64

// ---- bucketed counting sort params ----
#define BUCKET_SHIFT 8
#define NB_BUCKETS ((N_NODES + 255) / 256)   // 391
#define BUCKET_CAP 6144
#define EPT 32
#define EPB (256 * EPT)                      // 8192
#define NBLK_A ((N_EDGES + EPB - 1) / EPB)   // 196

typedef short bf16x8 __attribute__((ext_vector_type(8)));
typedef float f32x4  __attribute__((ext_vector_type(4)));
typedef float f32x2  __attribute__((ext_vector_type(2)));

__device__ __forceinline__ unsigned short f2bf(float f) {
    union { float f; unsigned u; } v; v.f = f;
    unsigned r = v.u + 0x7FFF + ((v.u >> 16) & 1);   // RNE
    return (unsigned short)(r >> 16);
}
__device__ __forceinline__ float bf2f_lo(unsigned u) {
    union { unsigned u; float f; } v; v.u = u << 16; return v.f;
}
__device__ __forceinline__ float bf2f_hi(unsigned u) {
    union { unsigned u; float f; } v; v.u = u & 0xFFFF0000u; return v.f;
}

// ---------------- CSR build: bucketed counting sort ----------------

__global__ __launch_bounds__(256) void bucket_scatter(
    const int* __restrict__ src, const int* __restrict__ dst,
    int* __restrict__ bucketCursor, unsigned* __restrict__ bucketData)
{
    __shared__ int cnt[NB_BUCKETS];
    __shared__ int base[NB_BUCKETS];
    int t = threadIdx.x;
    for (int i = t; i < NB_BUCKETS; i += 256) cnt[i] = 0;
    __syncthreads();
    int start = blockIdx.x * EPB;
#pragma unroll 4
    for (int j = 0; j < EPT; ++j) {
        int i = start + j * 256 + t;
        if (i < N_EDGES) atomicAdd(&cnt[dst[i] >> BUCKET_SHIFT], 1);
    }
    __syncthreads();
    for (int i = t; i < NB_BUCKETS; i += 256) {
        int c = cnt[i];
        base[i] = (c > 0) ? atomicAdd(&bucketCursor[i], c) : 0;
        cnt[i] = 0;
    }
    __syncthreads();
#pragma unroll 4
    for (int j = 0; j < EPT; ++j) {
        int i = start + j * 256 + t;
        if (i < N_EDGES) {
            int d = dst[i];
            int b = d >> BUCKET_SHIFT;
            int r = atomicAdd(&cnt[b], 1);
            int pos = base[b] + r;
            if (pos < BUCKET_CAP)
                bucketData[(size_t)b * BUCKET_CAP + pos] =
                    ((unsigned)(d & 255) << 17) | (unsigned)src[i];
        }
    }
}

__global__ void bucket_scan(const int* __restrict__ bucketCursor,
                            int* __restrict__ bucketStart, int* __restrict__ rowStart)
{
    __shared__ int s[512];
    int t = threadIdx.x;
    int v = (t < NB_BUCKETS) ? bucketCursor[t] : 0;
    s[t] = v;
    __syncthreads();
    for (int off = 1; off < 512; off <<= 1) {
        int tmp = (t >= off) ? s[t - off] : 0;
        __syncthreads();
        s[t] += tmp;
        __syncthreads();
    }
    if (t < NB_BUCKETS) bucketStart[t] = s[t] - v;
    if (t == 511) rowStart[N_NODES] = s[511];
}

__global__ __launch_bounds__(256) void bucket_to_csr(
    const unsigned* __restrict__ bucketData, const int* __restrict__ bucketCursor,
    const int* __restrict__ bucketStart,
    int* __restrict__ rowStart, int* __restrict__ srcSorted)
{
    __shared__ unsigned ent[BUCKET_CAP];
    __shared__ int hcnt[256];
    __shared__ int excl[256];
    __shared__ int ss[256];
    int b = blockIdx.x;
    int t = threadIdx.x;
    int n = bucketCursor[b];
    if (n > BUCKET_CAP) n = BUCKET_CAP;
    int gbase = bucketStart[b];
    hcnt[t] = 0;
    __syncthreads();
    for (int i = t; i < n; i += 256) {
        unsigned v = bucketData[(size_t)b * BUCKET_CAP + i];
        ent[i] = v;
        atomicAdd(&hcnt[v >> 17], 1);
    }
    __syncthreads();
    int myc = hcnt[t];
    ss[t] = myc;
    __syncthreads();
    for (int off = 1; off < 256; off <<= 1) {
        int tmp = (t >= off) ? ss[t - off] : 0;
        __syncthreads();
        ss[t] += tmp;
        __syncthreads();
    }
    excl[t] = ss[t] - myc;
    int node = b * 256 + t;
    if (node < N_NODES) rowStart[node] = gbase + excl[t];
    hcnt[t] = 0;
    __syncthreads();
    for (int i = t; i < n; i += 256) {
        unsigned v = ent[i];
        int d = v >> 17;
        int r = atomicAdd(&hcnt[d], 1);
        srcSorted[gbase + excl[d] + r] = (int)(v & 0x1FFFF);
    }
}

// ---------------- dtype prep ----------------

// x (fp32) -> xb (bf16 pairs, N x 64 uints) AND xq (fp8 e4m3, N x 32 uints)
__global__ void convert_x_kernel(const float* __restrict__ x, unsigned* __restrict__ xb,
                                 unsigned* __restrict__ xq) {
    long long t = (long long)blockIdx.x * blockDim.x + threadIdx.x;   // one per 4 floats
    if (t >= (long long)N_NODES * 32) return;
    float4 v = ((const float4*)x)[t];
    unsigned u0 = (unsigned)f2bf(v.x) | ((unsigned)f2bf(v.y) << 16);
    unsigned u1 = (unsigned)f2bf(v.z) | ((unsigned)f2bf(v.w) << 16);
    ((uint2*)xb)[t] = make_uint2(u0, u1);
    int q = 0;
    q = __builtin_amdgcn_cvt_pk_fp8_f32(v.x, v.y, q, false);  // bytes 0,1
    q = __builtin_amdgcn_cvt_pk_fp8_f32(v.z, v.w, q, true);   // bytes 2,3
    xq[t] = (unsigned)q;
}

// B matrices -> MFMA fragment order (bf16).
__global__ void prep_b_kernel(const float* __restrict__ Wl1, const float* __restrict__ Wr1,
                              const float* __restrict__ Wl2, const float* __restrict__ Wr2,
                              unsigned short* __restrict__ B1, unsigned short* __restrict__ B2) {
    int e = blockIdx.x * blockDim.x + threadIdx.x;
    if (e < 256 * 128) {
        int k = e >> 7, n = e & 127;
        float w = (k < 128) ? Wl1[k * 128 + n] : Wr1[(k - 128) * 128 + n];
        int kstep = k >> 5, quad = (k >> 3) & 3, j = k & 7;
        int lane = quad * 16 + (n & 15), ntile = n >> 4;
        B1[((kstep * 8 + ntile) * 64 + lane) * 8 + j] = f2bf(w);
    } else {
        int e2 = e - 256 * 128;
        if (e2 >= 128 * 128) return;
        int k = e2 >> 7, n = e2 & 127;
        float w = (n < 64) ? Wl2[k * 64 + n] : Wr2[k * 64 + (n - 64)];
        int kstep = k >> 5, quad = (k >> 3) & 3, j = k & 7;
        int lane = quad * 16 + (n & 15), ntile = n >> 4;
        B2[((kstep * 8 + ntile) * 64 + lane) * 8 + j] = f2bf(w);
    }
}

// ---------------- Aggregation ----------------

// agg1: fp8 gather. 32 lanes cover one 128 B row; wave handles 2 edges/iter.
__global__ void agg1_kernel(const unsigned* __restrict__ xq, const int* __restrict__ rowStart,
                            const int* __restrict__ srcSorted, unsigned* __restrict__ meanb) {
    int wave = threadIdx.x >> 6;
    int lane = threadIdx.x & 63;
    int node = blockIdx.x * 4 + wave;
    if (node >= N_NODES) return;
    int b = rowStart[node], e = rowStart[node + 1];
    int half = lane >> 5;      // which edge of the pair
    int lq = lane & 31;        // uint index in row (features 4lq..4lq+3)
    float a0 = 0.f, a1 = 0.f, a2 = 0.f, a3 = 0.f;
    int i = b;
    for (; i + 4 <= e; i += 4) {
        int sA = srcSorted[i + half];
        int sB = srcSorted[i + 2 + half];
        unsigned uA = xq[(size_t)sA * 32 + lq];
        unsigned uB = xq[(size_t)sB * 32 + lq];
        f32x2 lA = __builtin_amdgcn_cvt_pk_f32_fp8(uA, false);
        f32x2 hA = __builtin_amdgcn_cvt_pk_f32_fp8(uA, true);
        f32x2 lB = __builtin_amdgcn_cvt_pk_f32_fp8(uB, false);
        f32x2 hB = __builtin_amdgcn_cvt_pk_f32_fp8(uB, true);
        a0 += lA.x + lB.x; a1 += lA.y + lB.y;
        a2 += hA.x + hB.x; a3 += hA.y + hB.y;
    }
    for (; i < e; i += 2) {
        int idx = i + half;
        bool valid = idx < e;
        int s = srcSorted[valid ? idx : i];
        unsigned u = xq[(size_t)s * 32 + lq];
        float w = valid ? 1.f : 0.f;
        f32x2 lo = __builtin_amdgcn_cvt_pk_f32_fp8(u, false);
        f32x2 hi = __builtin_amdgcn_cvt_pk_f32_fp8(u, true);
        a0 = fmaf(lo.x, w, a0); a1 = fmaf(lo.y, w, a1);
        a2 = fmaf(hi.x, w, a2); a3 = fmaf(hi.y, w, a3);
    }
    a0 += __shfl_down(a0, 32);
    a1 += __shfl_down(a1, 32);
    a2 += __shfl_down(a2, 32);
    a3 += __shfl_down(a3, 32);
    if (lane < 32) {
        float inv = 1.0f / (float)max(e - b, 1);
        unsigned p0 = (unsigned)f2bf(a0 * inv) | ((unsigned)f2bf(a1 * inv) << 16);
        unsigned p1 = (unsigned)f2bf(a2 * inv) | ((unsigned)f2bf(a3 * inv) << 16);
        ((uint2*)(meanb + (size_t)node * 64))[lane] = make_uint2(p0, p1);
    }
}

// agg2: bf16 gather. 32 lanes cover one 128 B row (uint = 2 features), 2 edges/iter.
__global__ void agg2_kernel(const unsigned* __restrict__ p, const float* __restrict__ q,
                            const int* __restrict__ rowStart, const int* __restrict__ srcSorted,
                            float* __restrict__ out) {
    int wave = threadIdx.x >> 6;
    int lane = threadIdx.x & 63;
    int node = blockIdx.x * 4 + wave;
    if (node >= N_NODES) return;
    int b = rowStart[node], e = rowStart[node + 1];
    int half = lane >> 5;
    int lq = lane & 31;        // features 2lq, 2lq+1
    float a0 = 0.f, a1 = 0.f;
    int i = b;
    for (; i + 4 <= e; i += 4) {
        int sA = srcSorted[i + half];
        int sB = srcSorted[i + 2 + half];
        unsigned uA = p[(size_t)sA * 32 + lq];
        unsigned uB = p[(size_t)sB * 32 + lq];
        a0 += bf2f_lo(uA) + bf2f_lo(uB);
        a1 += bf2f_hi(uA) + bf2f_hi(uB);
    }
    for (; i < e; i += 2) {
        int idx = i + half;
        bool valid = idx < e;
        int s = srcSorted[valid ? idx : i];
        unsigned u = p[(size_t)s * 32 + lq];
        float w = valid ? 1.f : 0.f;
        a0 = fmaf(bf2f_lo(u), w, a0);
        a1 = fmaf(bf2f_hi(u), w, a1);
    }
    a0 += __shfl_down(a0, 32);
    a1 += __shfl_down(a1, 32);
    if (lane < 32) {
        float inv = 1.0f / (float)max(e - b, 1);
        f32x2 qv = ((const f32x2*)(q + (size_t)node * 64))[lq];
        float z0 = a0 * inv + qv.x;
        float z1 = a1 * inv + qv.y;
        f32x2 o;
        o.x = 1.0f / (1.0f + __expf(-z0));
        o.y = 1.0f / (1.0f + __expf(-z1));
        ((f32x2*)(out + (size_t)node * 64))[lq] = o;
    }
}

// ---------------- MFMA GEMMs ----------------

__global__ __launch_bounds__(256) void gemm1_kernel(
    const unsigned short* __restrict__ meanb, const unsigned short* __restrict__ xb,
    const unsigned short* __restrict__ B1, const float* __restrict__ bl1,
    unsigned short* __restrict__ h)
{
    __shared__ int ldsB[16384];
    int tid = threadIdx.x;
    for (int i = tid; i < 4096; i += 256)
        ((int4*)ldsB)[i] = ((const int4*)B1)[i];
    __syncthreads();

    int lane = tid & 63;
    int waveId = tid >> 6;
    int m = lane & 15, quad = lane >> 4;
    int rowBase = blockIdx.x * 64 + waveId * 16;
    int arow = rowBase + m;
    bool rowOk = arow < N_NODES;

    f32x4 acc[8];
#pragma unroll
    for (int t = 0; t < 8; ++t) acc[t] = (f32x4){0.f, 0.f, 0.f, 0.f};

    const bf16x8* lds = (const bf16x8*)ldsB;
#pragma unroll
    for (int kstep = 0; kstep < 8; ++kstep) {
        int kglob = kstep * 32 + quad * 8;
        bf16x8 afrag = (bf16x8)(short)0;
        if (rowOk) {
            const unsigned short* ap = (kglob < 128)
                ? (meanb + (size_t)arow * 128 + kglob)
                : (xb + (size_t)arow * 128 + (kglob - 128));
            afrag = *(const bf16x8*)ap;
        }
#pragma unroll
        for (int nt = 0; nt < 8; ++nt) {
            bf16x8 bfrag = lds[(kstep * 8 + nt) * 64 + lane];
            acc[nt] = __builtin_amdgcn_mfma_f32_16x16x32_bf16(afrag, bfrag, acc[nt], 0, 0, 0);
        }
    }

#pragma unroll
    for (int nt = 0; nt < 8; ++nt) {
        int col = nt * 16 + m;
        float bias = bl1[col];
#pragma unroll
        for (int r = 0; r < 4; ++r) {
            int row = rowBase + quad * 4 + r;
            if (row < N_NODES) {
                float v = fmaxf(acc[nt][r] + bias, 0.f);
                h[(size_t)row * 128 + col] = f2bf(v);
            }
        }
    }
}

__global__ __launch_bounds__(256) void gemm2_kernel(
    const unsigned short* __restrict__ h, const unsigned short* __restrict__ B2,
    const float* __restrict__ bl2,
    unsigned short* __restrict__ p, float* __restrict__ q)
{
    __shared__ int ldsB[8192];
    int tid = threadIdx.x;
    for (int i = tid; i < 2048; i += 256)
        ((int4*)ldsB)[i] = ((const int4*)B2)[i];
    __syncthreads();

    int lane = tid & 63;
    int waveId = tid >> 6;
    int m = lane & 15, quad = lane >> 4;
    int rowBase = blockIdx.x * 64 + waveId * 16;
    int arow = rowBase + m;
    bool rowOk = arow < N_NODES;

    f32x4 acc[8];
#pragma unroll
    for (int t = 0; t < 8; ++t) acc[t] = (f32x4){0.f, 0.f, 0.f, 0.f};

    const bf16x8* lds = (const bf16x8*)ldsB;
#pragma unroll
    for (int kstep = 0; kstep < 4; ++kstep) {
        int kglob = kstep * 32 + quad * 8;
        bf16x8 afrag = (bf16x8)(short)0;
        if (rowOk)
            afrag = *(const bf16x8*)(h + (size_t)arow * 128 + kglob);
#pragma unroll
        for (int nt = 0; nt < 8; ++nt) {
            bf16x8 bfrag = lds[(kstep * 8 + nt) * 64 + lane];
            acc[nt] = __builtin_amdgcn_mfma_f32_16x16x32_bf16(afrag, bfrag, acc[nt], 0, 0, 0);
        }
    }

#pragma unroll
    for (int nt = 0; nt < 8; ++nt) {
        int col = nt * 16 + m;
        float bias = (col >= 64) ? bl2[col - 64] : 0.f;
#pragma unroll
        for (int r = 0; r < 4; ++r) {
            int row = rowBase + quad * 4 + r;
            if (row < N_NODES) {
                float v = acc[nt][r];
                if (col < 64)
                    p[(size_t)row * 64 + col] = f2bf(v);
                else
                    q[(size_t)row * 64 + (col - 64)] = v + bias;
            }
        }
    }
}

// ---------------- launch ----------------

extern "C" void kernel_launch(void* const* d_in, const int* in_sizes, int n_in,
                              void* d_out, int out_size, void* d_ws, size_t ws_size,
                              hipStream_t stream) {
    const float* x   = (const float*)d_in[0];
    const int*   ei  = (const int*)d_in[1];
    const float* Wl1 = (const float*)d_in[2];
    const float* bl1 = (const float*)d_in[3];
    const float* Wr1 = (const float*)d_in[4];
    const float* Wl2 = (const float*)d_in[5];
    const float* bl2 = (const float*)d_in[6];
    const float* Wr2 = (const float*)d_in[7];
    float* out = (float*)d_out;

    const int* src = ei;
    const int* dst = ei + N_EDGES;

    char* ws = (char*)d_ws;
    size_t off = 0;
    auto carve = [&](size_t bytes) -> void* {
        void* ptr = ws + off;
        off = (off + bytes + 255) & ~(size_t)255;
        return ptr;
    };
    int* rowStart     = (int*)carve((N_NODES + 1) * sizeof(int));
    int* bucketCursor = (int*)carve(NB_BUCKETS * sizeof(int));
    int* bucketStart  = (int*)carve(NB_BUCKETS * sizeof(int));
    unsigned* bucketData = (unsigned*)carve((size_t)NB_BUCKETS * BUCKET_CAP * sizeof(unsigned));
    int* srcSorted    = (int*)carve(N_EDGES * sizeof(int));
    unsigned* xb      = (unsigned*)carve((size_t)N_NODES * 64 * sizeof(unsigned));   // bf16 x
    unsigned* xq      = (unsigned*)carve((size_t)N_NODES * 32 * sizeof(unsigned));   // fp8 x
    unsigned* meanb   = (unsigned*)carve((size_t)N_NODES * 64 * sizeof(unsigned));
    unsigned short* h = (unsigned short*)carve((size_t)N_NODES * 128 * sizeof(short));
    unsigned short* B1 = (unsigned short*)carve(256 * 128 * sizeof(short));
    unsigned short* B2 = (unsigned short*)carve(128 * 128 * sizeof(short));
    unsigned short* p = (unsigned short*)meanb;   // overlay: meanb dead after gemm1
    float* q = (float*)xb;                        // overlay: xb dead after gemm1

    // 1. CSR build
    hipMemsetAsync(bucketCursor, 0, NB_BUCKETS * sizeof(int), stream);
    bucket_scatter<<<NBLK_A, 256, 0, stream>>>(src, dst, bucketCursor, bucketData);
    bucket_scan<<<1, 512, 0, stream>>>(bucketCursor, bucketStart, rowStart);
    bucket_to_csr<<<NB_BUCKETS, 256, 0, stream>>>(bucketData, bucketCursor, bucketStart,
                                                  rowStart, srcSorted);

    // 2. dtype prep
    convert_x_kernel<<<(N_NODES * 32 + 255) / 256, 256, 0, stream>>>(x, xb, xq);
    prep_b_kernel<<<(256 * 128 + 128 * 128 + 255) / 256, 256, 0, stream>>>(
        Wl1, Wr1, Wl2, Wr2, B1, B2);

    // 3. layer 1
    agg1_kernel<<<(N_NODES + 3) / 4, 256, 0, stream>>>(xq, rowStart, srcSorted, meanb);
    gemm1_kernel<<<(N_NODES + 63) / 64, 256, 0, stream>>>(
        (const unsigned short*)meanb, (const unsigned short*)xb, B1, bl1, h);

    // 4. layer 2
    gemm2_kernel<<<(N_NODES + 63) / 64, 256, 0, stream>>>(h, B2, bl2, p, q);
    agg2_kernel<<<(N_NODES + 3) / 4, 256, 0, stream>>>((const unsigned*)p, q,
                                                       rowStart, srcSorted, out);
}

// Round 5
// 324.193 us; speedup vs baseline: 2.3080x; 1.0845x over previous
//
#include <hip/hip_runtime.h>
#include <math.h>

#define N_NODES 100000
#define N_EDGES 1600000
#define D_IN    128
#define HIDDEN  128
#define D_OUT   64

// ---- bucketed counting sort params ----
#define BUCKET_SHIFT 8
#define NB_BUCKETS ((N_NODES + 255) / 256)   // 391
#define BUCKET_CAP 6144
#define EPT 32
#define EPB (256 * EPT)                      // 8192
#define NBLK_A ((N_EDGES + EPB - 1) / EPB)   // 196

typedef short bf16x8 __attribute__((ext_vector_type(8)));
typedef float f32x4  __attribute__((ext_vector_type(4)));
typedef float f32x2  __attribute__((ext_vector_type(2)));

__device__ __forceinline__ unsigned short f2bf(float f) {
    union { float f; unsigned u; } v; v.f = f;
    unsigned r = v.u + 0x7FFF + ((v.u >> 16) & 1);   // RNE
    return (unsigned short)(r >> 16);
}
__device__ __forceinline__ float bf2f_lo(unsigned u) {
    union { unsigned u; float f; } v; v.u = u << 16; return v.f;
}
__device__ __forceinline__ float bf2f_hi(unsigned u) {
    union { unsigned u; float f; } v; v.u = u & 0xFFFF0000u; return v.f;
}

// ---------------- CSR build: bucketed counting sort ----------------

__global__ __launch_bounds__(256) void bucket_scatter(
    const int* __restrict__ src, const int* __restrict__ dst,
    int* __restrict__ bucketCursor, unsigned* __restrict__ bucketData)
{
    __shared__ int cnt[NB_BUCKETS];
    __shared__ int base[NB_BUCKETS];
    int t = threadIdx.x;
    for (int i = t; i < NB_BUCKETS; i += 256) cnt[i] = 0;
    __syncthreads();
    int start = blockIdx.x * EPB;
#pragma unroll 4
    for (int j = 0; j < EPT; ++j) {
        int i = start + j * 256 + t;
        if (i < N_EDGES) atomicAdd(&cnt[dst[i] >> BUCKET_SHIFT], 1);
    }
    __syncthreads();
    for (int i = t; i < NB_BUCKETS; i += 256) {
        int c = cnt[i];
        base[i] = (c > 0) ? atomicAdd(&bucketCursor[i], c) : 0;
        cnt[i] = 0;
    }
    __syncthreads();
#pragma unroll 4
    for (int j = 0; j < EPT; ++j) {
        int i = start + j * 256 + t;
        if (i < N_EDGES) {
            int d = dst[i];
            int b = d >> BUCKET_SHIFT;
            int r = atomicAdd(&cnt[b], 1);
            int pos = base[b] + r;
            if (pos < BUCKET_CAP)
                bucketData[(size_t)b * BUCKET_CAP + pos] =
                    ((unsigned)(d & 255) << 17) | (unsigned)src[i];
        }
    }
}

__global__ void bucket_scan(const int* __restrict__ bucketCursor,
                            int* __restrict__ bucketStart, int* __restrict__ rowStart)
{
    __shared__ int s[512];
    int t = threadIdx.x;
    int v = (t < NB_BUCKETS) ? bucketCursor[t] : 0;
    s[t] = v;
    __syncthreads();
    for (int off = 1; off < 512; off <<= 1) {
        int tmp = (t >= off) ? s[t - off] : 0;
        __syncthreads();
        s[t] += tmp;
        __syncthreads();
    }
    if (t < NB_BUCKETS) bucketStart[t] = s[t] - v;
    if (t == 511) rowStart[N_NODES] = s[511];
}

__global__ __launch_bounds__(256) void bucket_to_csr(
    const unsigned* __restrict__ bucketData, const int* __restrict__ bucketCursor,
    const int* __restrict__ bucketStart,
    int* __restrict__ rowStart, int* __restrict__ srcSorted)
{
    __shared__ unsigned ent[BUCKET_CAP];
    __shared__ int hcnt[256];
    __shared__ int excl[256];
    __shared__ int ss[256];
    int b = blockIdx.x;
    int t = threadIdx.x;
    int n = bucketCursor[b];
    if (n > BUCKET_CAP) n = BUCKET_CAP;
    int gbase = bucketStart[b];
    hcnt[t] = 0;
    __syncthreads();
    for (int i = t; i < n; i += 256) {
        unsigned v = bucketData[(size_t)b * BUCKET_CAP + i];
        ent[i] = v;
        atomicAdd(&hcnt[v >> 17], 1);
    }
    __syncthreads();
    int myc = hcnt[t];
    ss[t] = myc;
    __syncthreads();
    for (int off = 1; off < 256; off <<= 1) {
        int tmp = (t >= off) ? ss[t - off] : 0;
        __syncthreads();
        ss[t] += tmp;
        __syncthreads();
    }
    excl[t] = ss[t] - myc;
    int node = b * 256 + t;
    if (node < N_NODES) rowStart[node] = gbase + excl[t];
    hcnt[t] = 0;
    __syncthreads();
    for (int i = t; i < n; i += 256) {
        unsigned v = ent[i];
        int d = v >> 17;
        int r = atomicAdd(&hcnt[d], 1);
        srcSorted[gbase + excl[d] + r] = (int)(v & 0x1FFFF);
    }
}

// ---------------- dtype prep ----------------

// x (fp32) -> xb (bf16 pairs, N x 64 uints) AND xq (fp8 e4m3, N x 32 uints)
__global__ void convert_x_kernel(const float* __restrict__ x, unsigned* __restrict__ xb,
                                 unsigned* __restrict__ xq) {
    long long t = (long long)blockIdx.x * blockDim.x + threadIdx.x;   // one per 4 floats
    if (t >= (long long)N_NODES * 32) return;
    float4 v = ((const float4*)x)[t];
    unsigned u0 = (unsigned)f2bf(v.x) | ((unsigned)f2bf(v.y) << 16);
    unsigned u1 = (unsigned)f2bf(v.z) | ((unsigned)f2bf(v.w) << 16);
    ((uint2*)xb)[t] = make_uint2(u0, u1);
    int q = 0;
    q = __builtin_amdgcn_cvt_pk_fp8_f32(v.x, v.y, q, false);
    q = __builtin_amdgcn_cvt_pk_fp8_f32(v.z, v.w, q, true);
    xq[t] = (unsigned)q;
}

// B matrices -> MFMA fragment order (bf16).
__global__ void prep_b_kernel(const float* __restrict__ Wl1, const float* __restrict__ Wr1,
                              const float* __restrict__ Wl2, const float* __restrict__ Wr2,
                              unsigned short* __restrict__ B1, unsigned short* __restrict__ B2) {
    int e = blockIdx.x * blockDim.x + threadIdx.x;
    if (e < 256 * 128) {
        int k = e >> 7, n = e & 127;
        float w = (k < 128) ? Wl1[k * 128 + n] : Wr1[(k - 128) * 128 + n];
        int kstep = k >> 5, quad = (k >> 3) & 3, j = k & 7;
        int lane = quad * 16 + (n & 15), ntile = n >> 4;
        B1[((kstep * 8 + ntile) * 64 + lane) * 8 + j] = f2bf(w);
    } else {
        int e2 = e - 256 * 128;
        if (e2 >= 128 * 128) return;
        int k = e2 >> 7, n = e2 & 127;
        float w = (n < 64) ? Wl2[k * 64 + n] : Wr2[k * 64 + (n - 64)];
        int kstep = k >> 5, quad = (k >> 3) & 3, j = k & 7;
        int lane = quad * 16 + (n & 15), ntile = n >> 4;
        B2[((kstep * 8 + ntile) * 64 + lane) * 8 + j] = f2bf(w);
    }
}

// ---------------- Aggregation ----------------

// agg1: fp8 gather, 16 lanes/edge (uint2 = 8 features), 8 edges per iteration.
__global__ void agg1_kernel(const unsigned* __restrict__ xq, const int* __restrict__ rowStart,
                            const int* __restrict__ srcSorted, unsigned* __restrict__ meanb) {
    int wave = threadIdx.x >> 6;
    int lane = threadIdx.x & 63;
    int node = blockIdx.x * 4 + wave;
    if (node >= N_NODES) return;
    int b = rowStart[node], e = rowStart[node + 1];
    int g  = lane >> 4;    // edge group 0..3
    int lf = lane & 15;    // uint2 index in row; features 8lf..8lf+7
    float a0=0.f,a1=0.f,a2=0.f,a3=0.f,a4=0.f,a5=0.f,a6=0.f,a7=0.f;
    int i = b;
    for (; i + 8 <= e; i += 8) {
        int sA = srcSorted[i + g];
        int sB = srcSorted[i + 4 + g];
        uint2 uA = ((const uint2*)(xq + (size_t)sA * 32))[lf];
        uint2 uB = ((const uint2*)(xq + (size_t)sB * 32))[lf];
        f32x2 lAx = __builtin_amdgcn_cvt_pk_f32_fp8(uA.x, false);
        f32x2 hAx = __builtin_amdgcn_cvt_pk_f32_fp8(uA.x, true);
        f32x2 lAy = __builtin_amdgcn_cvt_pk_f32_fp8(uA.y, false);
        f32x2 hAy = __builtin_amdgcn_cvt_pk_f32_fp8(uA.y, true);
        f32x2 lBx = __builtin_amdgcn_cvt_pk_f32_fp8(uB.x, false);
        f32x2 hBx = __builtin_amdgcn_cvt_pk_f32_fp8(uB.x, true);
        f32x2 lBy = __builtin_amdgcn_cvt_pk_f32_fp8(uB.y, false);
        f32x2 hBy = __builtin_amdgcn_cvt_pk_f32_fp8(uB.y, true);
        a0 += lAx.x + lBx.x; a1 += lAx.y + lBx.y;
        a2 += hAx.x + hBx.x; a3 += hAx.y + hBx.y;
        a4 += lAy.x + lBy.x; a5 += lAy.y + lBy.y;
        a6 += hAy.x + hBy.x; a7 += hAy.y + hBy.y;
    }
    for (; i < e; i += 4) {
        int idx = i + g;
        bool valid = idx < e;
        int s = srcSorted[valid ? idx : i];
        uint2 u = ((const uint2*)(xq + (size_t)s * 32))[lf];
        float w = valid ? 1.f : 0.f;
        f32x2 lx = __builtin_amdgcn_cvt_pk_f32_fp8(u.x, false);
        f32x2 hx = __builtin_amdgcn_cvt_pk_f32_fp8(u.x, true);
        f32x2 ly = __builtin_amdgcn_cvt_pk_f32_fp8(u.y, false);
        f32x2 hy = __builtin_amdgcn_cvt_pk_f32_fp8(u.y, true);
        a0 = fmaf(lx.x, w, a0); a1 = fmaf(lx.y, w, a1);
        a2 = fmaf(hx.x, w, a2); a3 = fmaf(hx.y, w, a3);
        a4 = fmaf(ly.x, w, a4); a5 = fmaf(ly.y, w, a5);
        a6 = fmaf(hy.x, w, a6); a7 = fmaf(hy.y, w, a7);
    }
    a0 += __shfl_down(a0, 32); a1 += __shfl_down(a1, 32);
    a2 += __shfl_down(a2, 32); a3 += __shfl_down(a3, 32);
    a4 += __shfl_down(a4, 32); a5 += __shfl_down(a5, 32);
    a6 += __shfl_down(a6, 32); a7 += __shfl_down(a7, 32);
    a0 += __shfl_down(a0, 16); a1 += __shfl_down(a1, 16);
    a2 += __shfl_down(a2, 16); a3 += __shfl_down(a3, 16);
    a4 += __shfl_down(a4, 16); a5 += __shfl_down(a5, 16);
    a6 += __shfl_down(a6, 16); a7 += __shfl_down(a7, 16);
    if (lane < 16) {
        float inv = 1.0f / (float)max(e - b, 1);
        uint4 o;
        o.x = (unsigned)f2bf(a0 * inv) | ((unsigned)f2bf(a1 * inv) << 16);
        o.y = (unsigned)f2bf(a2 * inv) | ((unsigned)f2bf(a3 * inv) << 16);
        o.z = (unsigned)f2bf(a4 * inv) | ((unsigned)f2bf(a5 * inv) << 16);
        o.w = (unsigned)f2bf(a6 * inv) | ((unsigned)f2bf(a7 * inv) << 16);
        ((uint4*)(meanb + (size_t)node * 64))[lf] = o;
    }
}

// agg2: bf16 gather, 16 lanes/edge (uint2 = 4 features), 8 edges per iteration.
__global__ void agg2_kernel(const unsigned* __restrict__ p, const float* __restrict__ q,
                            const int* __restrict__ rowStart, const int* __restrict__ srcSorted,
                            float* __restrict__ out) {
    int wave = threadIdx.x >> 6;
    int lane = threadIdx.x & 63;
    int node = blockIdx.x * 4 + wave;
    if (node >= N_NODES) return;
    int b = rowStart[node], e = rowStart[node + 1];
    int g  = lane >> 4;    // edge group 0..3
    int lf = lane & 15;    // uint2 index in row; features 4lf..4lf+3
    float a0=0.f,a1=0.f,a2=0.f,a3=0.f;
    int i = b;
    for (; i + 8 <= e; i += 8) {
        int sA = srcSorted[i + g];
        int sB = srcSorted[i + 4 + g];
        uint2 uA = ((const uint2*)(p + (size_t)sA * 32))[lf];
        uint2 uB = ((const uint2*)(p + (size_t)sB * 32))[lf];
        a0 += bf2f_lo(uA.x) + bf2f_lo(uB.x);
        a1 += bf2f_hi(uA.x) + bf2f_hi(uB.x);
        a2 += bf2f_lo(uA.y) + bf2f_lo(uB.y);
        a3 += bf2f_hi(uA.y) + bf2f_hi(uB.y);
    }
    for (; i < e; i += 4) {
        int idx = i + g;
        bool valid = idx < e;
        int s = srcSorted[valid ? idx : i];
        uint2 u = ((const uint2*)(p + (size_t)s * 32))[lf];
        float w = valid ? 1.f : 0.f;
        a0 = fmaf(bf2f_lo(u.x), w, a0);
        a1 = fmaf(bf2f_hi(u.x), w, a1);
        a2 = fmaf(bf2f_lo(u.y), w, a2);
        a3 = fmaf(bf2f_hi(u.y), w, a3);
    }
    a0 += __shfl_down(a0, 32); a1 += __shfl_down(a1, 32);
    a2 += __shfl_down(a2, 32); a3 += __shfl_down(a3, 32);
    a0 += __shfl_down(a0, 16); a1 += __shfl_down(a1, 16);
    a2 += __shfl_down(a2, 16); a3 += __shfl_down(a3, 16);
    if (lane < 16) {
        float inv = 1.0f / (float)max(e - b, 1);
        f32x4 qv = ((const f32x4*)(q + (size_t)node * 64))[lf];
        f32x4 o;
        o.x = 1.0f / (1.0f + __expf(-(a0 * inv + qv.x)));
        o.y = 1.0f / (1.0f + __expf(-(a1 * inv + qv.y)));
        o.z = 1.0f / (1.0f + __expf(-(a2 * inv + qv.z)));
        o.w = 1.0f / (1.0f + __expf(-(a3 * inv + qv.w)));
        ((f32x4*)(out + (size_t)node * 64))[lf] = o;
    }
}

// ---------------- MFMA GEMMs ----------------

__global__ __launch_bounds__(256) void gemm1_kernel(
    const unsigned short* __restrict__ meanb, const unsigned short* __restrict__ xb,
    const unsigned short* __restrict__ B1, const float* __restrict__ bl1,
    unsigned short* __restrict__ h)
{
    __shared__ int ldsB[16384];
    int tid = threadIdx.x;
    for (int i = tid; i < 4096; i += 256)
        ((int4*)ldsB)[i] = ((const int4*)B1)[i];
    __syncthreads();

    int lane = tid & 63;
    int waveId = tid >> 6;
    int m = lane & 15, quad = lane >> 4;
    int rowBase = blockIdx.x * 64 + waveId * 16;
    int arow = rowBase + m;
    bool rowOk = arow < N_NODES;

    f32x4 acc[8];
#pragma unroll
    for (int t = 0; t < 8; ++t) acc[t] = (f32x4){0.f, 0.f, 0.f, 0.f};

    const bf16x8* lds = (const bf16x8*)ldsB;
#pragma unroll
    for (int kstep = 0; kstep < 8; ++kstep) {
        int kglob = kstep * 32 + quad * 8;
        bf16x8 afrag = (bf16x8)(short)0;
        if (rowOk) {
            const unsigned short* ap = (kglob < 128)
                ? (meanb + (size_t)arow * 128 + kglob)
                : (xb + (size_t)arow * 128 + (kglob - 128));
            afrag = *(const bf16x8*)ap;
        }
#pragma unroll
        for (int nt = 0; nt < 8; ++nt) {
            bf16x8 bfrag = lds[(kstep * 8 + nt) * 64 + lane];
            acc[nt] = __builtin_amdgcn_mfma_f32_16x16x32_bf16(afrag, bfrag, acc[nt], 0, 0, 0);
        }
    }

#pragma unroll
    for (int nt = 0; nt < 8; ++nt) {
        int col = nt * 16 + m;
        float bias = bl1[col];
#pragma unroll
        for (int r = 0; r < 4; ++r) {
            int row = rowBase + quad * 4 + r;
            if (row < N_NODES) {
                float v = fmaxf(acc[nt][r] + bias, 0.f);
                h[(size_t)row * 128 + col] = f2bf(v);
            }
        }
    }
}

__global__ __launch_bounds__(256) void gemm2_kernel(
    const unsigned short* __restrict__ h, const unsigned short* __restrict__ B2,
    const float* __restrict__ bl2,
    unsigned short* __restrict__ p, float* __restrict__ q)
{
    __shared__ int ldsB[8192];
    int tid = threadIdx.x;
    for (int i = tid; i < 2048; i += 256)
        ((int4*)ldsB)[i] = ((const int4*)B2)[i];
    __syncthreads();

    int lane = tid & 63;
    int waveId = tid >> 6;
    int m = lane & 15, quad = lane >> 4;
    int rowBase = blockIdx.x * 64 + waveId * 16;
    int arow = rowBase + m;
    bool rowOk = arow < N_NODES;

    f32x4 acc[8];
#pragma unroll
    for (int t = 0; t < 8; ++t) acc[t] = (f32x4){0.f, 0.f, 0.f, 0.f};

    const bf16x8* lds = (const bf16x8*)ldsB;
#pragma unroll
    for (int kstep = 0; kstep < 4; ++kstep) {
        int kglob = kstep * 32 + quad * 8;
        bf16x8 afrag = (bf16x8)(short)0;
        if (rowOk)
            afrag = *(const bf16x8*)(h + (size_t)arow * 128 + kglob);
#pragma unroll
        for (int nt = 0; nt < 8; ++nt) {
            bf16x8 bfrag = lds[(kstep * 8 + nt) * 64 + lane];
            acc[nt] = __builtin_amdgcn_mfma_f32_16x16x32_bf16(afrag, bfrag, acc[nt], 0, 0, 0);
        }
    }

#pragma unroll
    for (int nt = 0; nt < 8; ++nt) {
        int col = nt * 16 + m;
        float bias = (col >= 64) ? bl2[col - 64] : 0.f;
#pragma unroll
        for (int r = 0; r < 4; ++r) {
            int row = rowBase + quad * 4 + r;
            if (row < N_NODES) {
                float v = acc[nt][r];
                if (col < 64)
                    p[(size_t)row * 64 + col] = f2bf(v);
                else
                    q[(size_t)row * 64 + (col - 64)] = v + bias;
            }
        }
    }
}

// ---------------- launch ----------------

extern "C" void kernel_launch(void* const* d_in, const int* in_sizes, int n_in,
                              void* d_out, int out_size, void* d_ws, size_t ws_size,
                              hipStream_t stream) {
    const float* x   = (const float*)d_in[0];
    const int*   ei  = (const int*)d_in[1];
    const float* Wl1 = (const float*)d_in[2];
    const float* bl1 = (const float*)d_in[3];
    const float* Wr1 = (const float*)d_in[4];
    const float* Wl2 = (const float*)d_in[5];
    const float* bl2 = (const float*)d_in[6];
    const float* Wr2 = (const float*)d_in[7];
    float* out = (float*)d_out;

    const int* src = ei;
    const int* dst = ei + N_EDGES;

    char* ws = (char*)d_ws;
    size_t off = 0;
    auto carve = [&](size_t bytes) -> void* {
        void* ptr = ws + off;
        off = (off + bytes + 255) & ~(size_t)255;
        return ptr;
    };
    int* rowStart     = (int*)carve((N_NODES + 1) * sizeof(int));
    int* bucketCursor = (int*)carve(NB_BUCKETS * sizeof(int));
    int* bucketStart  = (int*)carve(NB_BUCKETS * sizeof(int));
    unsigned* bucketData = (unsigned*)carve((size_t)NB_BUCKETS * BUCKET_CAP * sizeof(unsigned));
    int* srcSorted    = (int*)carve(N_EDGES * sizeof(int));
    unsigned* xb      = (unsigned*)carve((size_t)N_NODES * 64 * sizeof(unsigned));   // bf16 x
    unsigned* xq      = (unsigned*)carve((size_t)N_NODES * 32 * sizeof(unsigned));   // fp8 x
    unsigned* meanb   = (unsigned*)carve((size_t)N_NODES * 64 * sizeof(unsigned));
    unsigned short* h = (unsigned short*)carve((size_t)N_NODES * 128 * sizeof(short));
    unsigned short* B1 = (unsigned short*)carve(256 * 128 * sizeof(short));
    unsigned short* B2 = (unsigned short*)carve(128 * 128 * sizeof(short));
    unsigned short* p = (unsigned short*)meanb;   // overlay: meanb dead after gemm1
    float* q = (float*)xb;                        // overlay: xb dead after gemm1

    // 1. CSR build
    hipMemsetAsync(bucketCursor, 0, NB_BUCKETS * sizeof(int), stream);
    bucket_scatter<<<NBLK_A, 256, 0, stream>>>(src, dst, bucketCursor, bucketData);
    bucket_scan<<<1, 512, 0, stream>>>(bucketCursor, bucketStart, rowStart);
    bucket_to_csr<<<NB_BUCKETS, 256, 0, stream>>>(bucketData, bucketCursor, bucketStart,
                                                  rowStart, srcSorted);

    // 2. dtype prep
    convert_x_kernel<<<(N_NODES * 32 + 255) / 256, 256, 0, stream>>>(x, xb, xq);
    prep_b_kernel<<<(256 * 128 + 128 * 128 + 255) / 256, 256, 0, stream>>>(
        Wl1, Wr1, Wl2, Wr2, B1, B2);

    // 3. layer 1
    agg1_kernel<<<(N_NODES + 3) / 4, 256, 0, stream>>>(xq, rowStart, srcSorted, meanb);
    gemm1_kernel<<<(N_NODES + 63) / 64, 256, 0, stream>>>(
        (const unsigned short*)meanb, (const unsigned short*)xb, B1, bl1, h);

    // 4. layer 2
    gemm2_kernel<<<(N_NODES + 63) / 64, 256, 0, stream>>>(h, B2, bl2, p, q);
    agg2_kernel<<<(N_NODES + 3) / 4, 256, 0, stream>>>((const unsigned*)p, q,
                                                       rowStart, srcSorted, out);
}

// Round 6
// 314.715 us; speedup vs baseline: 2.3775x; 1.0301x over previous
//
#include <hip/hip_runtime.h>
#include <math.h>

#define N_NODES 100000
#define N_EDGES 1600000
#define D_IN    128
#define HIDDEN  128
#define D_OUT   64

// ---- bucketed counting sort params ----
#define BUCKET_SHIFT 8
#define NB_BUCKETS ((N_NODES + 255) / 256)   // 391
#define BUCKET_CAP 6144
#define EPT 32
#define EPB (256 * EPT)                      // 8192
#define NBLK_SCATTER ((N_EDGES + EPB - 1) / EPB)   // 196
#define NBLK_CONVERT ((N_NODES * 32 + 255) / 256)  // 12500
#define NBLK_PREPB   ((256 * 128 + 128 * 128 + 255) / 256)  // 192

typedef short bf16x8 __attribute__((ext_vector_type(8)));
typedef float f32x4  __attribute__((ext_vector_type(4)));
typedef float f32x2  __attribute__((ext_vector_type(2)));
typedef _Float16 h2 __attribute__((ext_vector_type(2)));

#if defined(__has_builtin)
# if __has_builtin(__builtin_amdgcn_fdot2)
#  define USE_FDOT2 1
# endif
#endif
#ifndef USE_FDOT2
# define USE_FDOT2 0
#endif

__device__ __forceinline__ unsigned short f2bf(float f) {
    union { float f; unsigned u; } v; v.f = f;
    unsigned r = v.u + 0x7FFF + ((v.u >> 16) & 1);   // RNE
    return (unsigned short)(r >> 16);
}
__device__ __forceinline__ float bf2f_lo(unsigned u) {
    union { unsigned u; float f; } v; v.u = u << 16; return v.f;
}
__device__ __forceinline__ float bf2f_hi(unsigned u) {
    union { unsigned u; float f; } v; v.u = u & 0xFFFF0000u; return v.f;
}
__device__ __forceinline__ h2 as_h2(unsigned u) {
    union { unsigned u; h2 h; } c; c.u = u; return c.h;
}
__device__ __forceinline__ unsigned short f2h_bits(float f) {
    union { _Float16 h; unsigned short s; } c; c.h = (_Float16)f; return c.s;
}

// ---------------- K1: fused setup (scatter | convert | prep_b) ----------------

__global__ __launch_bounds__(256) void setup_fused(
    const int* __restrict__ src, const int* __restrict__ dst,
    int* __restrict__ bucketCursor, unsigned* __restrict__ bucketData,
    const float* __restrict__ x, unsigned* __restrict__ xb, unsigned* __restrict__ xq,
    const float* __restrict__ Wl1, const float* __restrict__ Wr1,
    const float* __restrict__ Wl2, const float* __restrict__ Wr2,
    unsigned short* __restrict__ B1, unsigned short* __restrict__ B2)
{
    __shared__ int cnt[NB_BUCKETS];
    __shared__ int base[NB_BUCKETS];
    int bid = blockIdx.x;
    int t = threadIdx.x;

    if (bid < NBLK_SCATTER) {
        // ---- bucket scatter ----
        for (int i = t; i < NB_BUCKETS; i += 256) cnt[i] = 0;
        __syncthreads();
        int start = bid * EPB;
#pragma unroll 4
        for (int j = 0; j < EPT; ++j) {
            int i = start + j * 256 + t;
            if (i < N_EDGES) atomicAdd(&cnt[dst[i] >> BUCKET_SHIFT], 1);
        }
        __syncthreads();
        for (int i = t; i < NB_BUCKETS; i += 256) {
            int c = cnt[i];
            base[i] = (c > 0) ? atomicAdd(&bucketCursor[i], c) : 0;
            cnt[i] = 0;
        }
        __syncthreads();
#pragma unroll 4
        for (int j = 0; j < EPT; ++j) {
            int i = start + j * 256 + t;
            if (i < N_EDGES) {
                int d = dst[i];
                int b = d >> BUCKET_SHIFT;
                int r = atomicAdd(&cnt[b], 1);
                int pos = base[b] + r;
                if (pos < BUCKET_CAP)
                    bucketData[(size_t)b * BUCKET_CAP + pos] =
                        ((unsigned)(d & 255) << 17) | (unsigned)src[i];
            }
        }
    } else if (bid < NBLK_SCATTER + NBLK_CONVERT) {
        // ---- convert x -> bf16 + fp8 ----
        long long g = (long long)(bid - NBLK_SCATTER) * 256 + t;   // one per 4 floats
        if (g < (long long)N_NODES * 32) {
            float4 v = ((const float4*)x)[g];
            unsigned u0 = (unsigned)f2bf(v.x) | ((unsigned)f2bf(v.y) << 16);
            unsigned u1 = (unsigned)f2bf(v.z) | ((unsigned)f2bf(v.w) << 16);
            ((uint2*)xb)[g] = make_uint2(u0, u1);
            int q = 0;
            q = __builtin_amdgcn_cvt_pk_fp8_f32(v.x, v.y, q, false);
            q = __builtin_amdgcn_cvt_pk_fp8_f32(v.z, v.w, q, true);
            xq[g] = (unsigned)q;
        }
    } else {
        // ---- prep B fragments ----
        int e = (bid - NBLK_SCATTER - NBLK_CONVERT) * 256 + t;
        if (e < 256 * 128) {
            int k = e >> 7, n = e & 127;
            float w = (k < 128) ? Wl1[k * 128 + n] : Wr1[(k - 128) * 128 + n];
            int kstep = k >> 5, quad = (k >> 3) & 3, j = k & 7;
            int lane = quad * 16 + (n & 15), ntile = n >> 4;
            B1[((kstep * 8 + ntile) * 64 + lane) * 8 + j] = f2bf(w);
        } else if (e < 256 * 128 + 128 * 128) {
            int e2 = e - 256 * 128;
            int k = e2 >> 7, n = e2 & 127;
            float w = (n < 64) ? Wl2[k * 64 + n] : Wr2[k * 64 + (n - 64)];
            int kstep = k >> 5, quad = (k >> 3) & 3, j = k & 7;
            int lane = quad * 16 + (n & 15), ntile = n >> 4;
            B2[((kstep * 8 + ntile) * 64 + lane) * 8 + j] = f2bf(w);
        }
    }
}

// ---------------- K2: bucket -> CSR (self-scanning) ----------------

__global__ __launch_bounds__(256) void bucket_to_csr(
    const unsigned* __restrict__ bucketData, const int* __restrict__ bucketCursor,
    int* __restrict__ rowStart, int* __restrict__ srcSorted)
{
    __shared__ unsigned ent[BUCKET_CAP];
    __shared__ int hcnt[256];
    __shared__ int excl[256];
    __shared__ int ss[256];
    __shared__ int red[256];
    int b = blockIdx.x;
    int t = threadIdx.x;

    // self-scan: gbase = sum of counts of buckets < b
    int partial = 0;
    for (int i = t; i < NB_BUCKETS; i += 256) {
        int c = bucketCursor[i];
        if (i < b) partial += c;
    }
    red[t] = partial;
    __syncthreads();
    for (int off = 128; off > 0; off >>= 1) {
        if (t < off) red[t] += red[t + off];
        __syncthreads();
    }
    int gbase = red[0];
    int n = bucketCursor[b];
    if (b == NB_BUCKETS - 1 && t == 0) rowStart[N_NODES] = gbase + n;
    if (n > BUCKET_CAP) n = BUCKET_CAP;

    hcnt[t] = 0;
    __syncthreads();
    for (int i = t; i < n; i += 256) {
        unsigned v = bucketData[(size_t)b * BUCKET_CAP + i];
        ent[i] = v;
        atomicAdd(&hcnt[v >> 17], 1);
    }
    __syncthreads();
    int myc = hcnt[t];
    ss[t] = myc;
    __syncthreads();
    for (int off = 1; off < 256; off <<= 1) {
        int tmp = (t >= off) ? ss[t - off] : 0;
        __syncthreads();
        ss[t] += tmp;
        __syncthreads();
    }
    excl[t] = ss[t] - myc;
    int node = b * 256 + t;
    if (node < N_NODES) rowStart[node] = gbase + excl[t];
    hcnt[t] = 0;
    __syncthreads();
    for (int i = t; i < n; i += 256) {
        unsigned v = ent[i];
        int d = v >> 17;
        int r = atomicAdd(&hcnt[d], 1);
        srcSorted[gbase + excl[d] + r] = (int)(v & 0x1FFFF);
    }
}

// ---------------- K3: agg1 (fp8 gather, 16 lanes/edge, 8 edges/iter) ----------------

__global__ void agg1_kernel(const unsigned* __restrict__ xq, const int* __restrict__ rowStart,
                            const int* __restrict__ srcSorted, unsigned* __restrict__ meanb) {
    int wave = threadIdx.x >> 6;
    int lane = threadIdx.x & 63;
    int node = blockIdx.x * 4 + wave;
    if (node >= N_NODES) return;
    int b = rowStart[node], e = rowStart[node + 1];
    int g  = lane >> 4;
    int lf = lane & 15;
    float a0=0.f,a1=0.f,a2=0.f,a3=0.f,a4=0.f,a5=0.f,a6=0.f,a7=0.f;
    int i = b;
    for (; i + 8 <= e; i += 8) {
        int sA = srcSorted[i + g];
        int sB = srcSorted[i + 4 + g];
        uint2 uA = ((const uint2*)(xq + (size_t)sA * 32))[lf];
        uint2 uB = ((const uint2*)(xq + (size_t)sB * 32))[lf];
        f32x2 lAx = __builtin_amdgcn_cvt_pk_f32_fp8(uA.x, false);
        f32x2 hAx = __builtin_amdgcn_cvt_pk_f32_fp8(uA.x, true);
        f32x2 lAy = __builtin_amdgcn_cvt_pk_f32_fp8(uA.y, false);
        f32x2 hAy = __builtin_amdgcn_cvt_pk_f32_fp8(uA.y, true);
        f32x2 lBx = __builtin_amdgcn_cvt_pk_f32_fp8(uB.x, false);
        f32x2 hBx = __builtin_amdgcn_cvt_pk_f32_fp8(uB.x, true);
        f32x2 lBy = __builtin_amdgcn_cvt_pk_f32_fp8(uB.y, false);
        f32x2 hBy = __builtin_amdgcn_cvt_pk_f32_fp8(uB.y, true);
        a0 += lAx.x + lBx.x; a1 += lAx.y + lBx.y;
        a2 += hAx.x + hBx.x; a3 += hAx.y + hBx.y;
        a4 += lAy.x + lBy.x; a5 += lAy.y + lBy.y;
        a6 += hAy.x + hBy.x; a7 += hAy.y + hBy.y;
    }
    for (; i < e; i += 4) {
        int idx = i + g;
        bool valid = idx < e;
        int s = srcSorted[valid ? idx : i];
        uint2 u = ((const uint2*)(xq + (size_t)s * 32))[lf];
        float w = valid ? 1.f : 0.f;
        f32x2 lx = __builtin_amdgcn_cvt_pk_f32_fp8(u.x, false);
        f32x2 hx = __builtin_amdgcn_cvt_pk_f32_fp8(u.x, true);
        f32x2 ly = __builtin_amdgcn_cvt_pk_f32_fp8(u.y, false);
        f32x2 hy = __builtin_amdgcn_cvt_pk_f32_fp8(u.y, true);
        a0 = fmaf(lx.x, w, a0); a1 = fmaf(lx.y, w, a1);
        a2 = fmaf(hx.x, w, a2); a3 = fmaf(hx.y, w, a3);
        a4 = fmaf(ly.x, w, a4); a5 = fmaf(ly.y, w, a5);
        a6 = fmaf(hy.x, w, a6); a7 = fmaf(hy.y, w, a7);
    }
    a0 += __shfl_down(a0, 32); a1 += __shfl_down(a1, 32);
    a2 += __shfl_down(a2, 32); a3 += __shfl_down(a3, 32);
    a4 += __shfl_down(a4, 32); a5 += __shfl_down(a5, 32);
    a6 += __shfl_down(a6, 32); a7 += __shfl_down(a7, 32);
    a0 += __shfl_down(a0, 16); a1 += __shfl_down(a1, 16);
    a2 += __shfl_down(a2, 16); a3 += __shfl_down(a3, 16);
    a4 += __shfl_down(a4, 16); a5 += __shfl_down(a5, 16);
    a6 += __shfl_down(a6, 16); a7 += __shfl_down(a7, 16);
    if (lane < 16) {
        float inv = 1.0f / (float)max(e - b, 1);
        uint4 o;
        o.x = (unsigned)f2bf(a0 * inv) | ((unsigned)f2bf(a1 * inv) << 16);
        o.y = (unsigned)f2bf(a2 * inv) | ((unsigned)f2bf(a3 * inv) << 16);
        o.z = (unsigned)f2bf(a4 * inv) | ((unsigned)f2bf(a5 * inv) << 16);
        o.w = (unsigned)f2bf(a6 * inv) | ((unsigned)f2bf(a7 * inv) << 16);
        ((uint4*)(meanb + (size_t)node * 64))[lf] = o;
    }
}

// ---------------- K4: fused GEMM (layer1 + layer2 premult), h stays in LDS ----------------
// Block = 256 thr (4 waves); wave handles 32 rows (two 16-row MFMA tiles).
// B fragments read directly from global (L2-hot, 96 KB total).
#define HSTRIDE 136   // shorts; 16B-aligned rows, spreads LDS banks

__global__ __launch_bounds__(256) void gemm12_kernel(
    const unsigned short* __restrict__ meanb, const unsigned short* __restrict__ xb,
    const unsigned short* __restrict__ B1f, const unsigned short* __restrict__ B2f,
    const float* __restrict__ bl1, const float* __restrict__ bl2,
    unsigned short* __restrict__ p, float* __restrict__ q)
{
    __shared__ unsigned short hTile[128 * HSTRIDE];   // 34 KB
    int tid = threadIdx.x;
    int lane = tid & 63;
    int waveId = tid >> 6;
    int m = lane & 15, quad = lane >> 4;
    int rowBase = blockIdx.x * 128 + waveId * 32;
    int arow0 = rowBase + m;
    int arow1 = rowBase + 16 + m;
    bool ok0 = arow0 < N_NODES, ok1 = arow1 < N_NODES;

    const bf16x8* B1v = (const bf16x8*)B1f;
    const bf16x8* B2v = (const bf16x8*)B2f;

    // ---- stage 1: h = relu([meanb|xb] @ B1 + bl1) ----
    f32x4 acc[2][8];
#pragma unroll
    for (int s = 0; s < 2; ++s)
#pragma unroll
        for (int t = 0; t < 8; ++t) acc[s][t] = (f32x4){0.f, 0.f, 0.f, 0.f};

#pragma unroll
    for (int kstep = 0; kstep < 8; ++kstep) {
        int kglob = kstep * 32 + quad * 8;
        bf16x8 af0 = (bf16x8)(short)0, af1 = (bf16x8)(short)0;
        const unsigned short* basePtr;
        int koff;
        if (kglob < 128) { basePtr = meanb == 0 ? 0 : meanb; koff = kglob; }
        else             { basePtr = xb;    koff = kglob - 128; }
        if (ok0) af0 = *(const bf16x8*)(basePtr + (size_t)arow0 * 128 + koff);
        if (ok1) af1 = *(const bf16x8*)(basePtr + (size_t)arow1 * 128 + koff);
#pragma unroll
        for (int nt = 0; nt < 8; ++nt) {
            bf16x8 bfrag = B1v[(kstep * 8 + nt) * 64 + lane];
            acc[0][nt] = __builtin_amdgcn_mfma_f32_16x16x32_bf16(af0, bfrag, acc[0][nt], 0, 0, 0);
            acc[1][nt] = __builtin_amdgcn_mfma_f32_16x16x32_bf16(af1, bfrag, acc[1][nt], 0, 0, 0);
        }
    }

    // epilogue 1 -> per-wave LDS tile (rows waveId*32 .. +31)
#pragma unroll
    for (int s = 0; s < 2; ++s)
#pragma unroll
        for (int nt = 0; nt < 8; ++nt) {
            int col = nt * 16 + m;
            float bias = bl1[col];
#pragma unroll
            for (int r = 0; r < 4; ++r) {
                int rowLocal = waveId * 32 + s * 16 + quad * 4 + r;
                float v = fmaxf(acc[s][nt][r] + bias, 0.f);
                hTile[rowLocal * HSTRIDE + col] = f2bf(v);
            }
        }

    // ---- stage 2: [p|q] = h @ B2 ----  (per-wave data; no __syncthreads needed)
    f32x4 acc2[2][8];
#pragma unroll
    for (int s = 0; s < 2; ++s)
#pragma unroll
        for (int t = 0; t < 8; ++t) acc2[s][t] = (f32x4){0.f, 0.f, 0.f, 0.f};

#pragma unroll
    for (int kstep = 0; kstep < 4; ++kstep) {
        int k0 = kstep * 32 + quad * 8;
        bf16x8 af0 = *(const bf16x8*)&hTile[(waveId * 32 + m) * HSTRIDE + k0];
        bf16x8 af1 = *(const bf16x8*)&hTile[(waveId * 32 + 16 + m) * HSTRIDE + k0];
#pragma unroll
        for (int nt = 0; nt < 8; ++nt) {
            bf16x8 bfrag = B2v[(kstep * 8 + nt) * 64 + lane];
            acc2[0][nt] = __builtin_amdgcn_mfma_f32_16x16x32_bf16(af0, bfrag, acc2[0][nt], 0, 0, 0);
            acc2[1][nt] = __builtin_amdgcn_mfma_f32_16x16x32_bf16(af1, bfrag, acc2[1][nt], 0, 0, 0);
        }
    }

#pragma unroll
    for (int s = 0; s < 2; ++s)
#pragma unroll
        for (int nt = 0; nt < 8; ++nt) {
            int col = nt * 16 + m;
            float bias = (col >= 64) ? bl2[col - 64] : 0.f;
#pragma unroll
            for (int r = 0; r < 4; ++r) {
                int row = rowBase + s * 16 + quad * 4 + r;
                if (row < N_NODES) {
                    float v = acc2[s][nt][r];
                    if (col < 64) {
#if USE_FDOT2
                        p[(size_t)row * 64 + col] = f2h_bits(v);
#else
                        p[(size_t)row * 64 + col] = f2bf(v);
#endif
                    } else {
                        q[(size_t)row * 64 + (col - 64)] = v + bias;
                    }
                }
            }
        }
}

// ---------------- K5: agg2 (p gather, 16 lanes/edge, 8 edges/iter) ----------------

__global__ void agg2_kernel(const unsigned* __restrict__ p, const float* __restrict__ q,
                            const int* __restrict__ rowStart, const int* __restrict__ srcSorted,
                            float* __restrict__ out) {
    int wave = threadIdx.x >> 6;
    int lane = threadIdx.x & 63;
    int node = blockIdx.x * 4 + wave;
    if (node >= N_NODES) return;
    int b = rowStart[node], e = rowStart[node + 1];
    int g  = lane >> 4;
    int lf = lane & 15;        // uint2 index; features 4lf..4lf+3
    float a0=0.f,a1=0.f,a2=0.f,a3=0.f;
#if USE_FDOT2
    const h2 ONE0 = {(_Float16)1.0f, (_Float16)0.0f};
    const h2 ONE1 = {(_Float16)0.0f, (_Float16)1.0f};
#endif
    int i = b;
    for (; i + 8 <= e; i += 8) {
        int sA = srcSorted[i + g];
        int sB = srcSorted[i + 4 + g];
        uint2 uA = ((const uint2*)(p + (size_t)sA * 32))[lf];
        uint2 uB = ((const uint2*)(p + (size_t)sB * 32))[lf];
#if USE_FDOT2
        a0 = __builtin_amdgcn_fdot2(as_h2(uA.x), ONE0, a0, false);
        a1 = __builtin_amdgcn_fdot2(as_h2(uA.x), ONE1, a1, false);
        a2 = __builtin_amdgcn_fdot2(as_h2(uA.y), ONE0, a2, false);
        a3 = __builtin_amdgcn_fdot2(as_h2(uA.y), ONE1, a3, false);
        a0 = __builtin_amdgcn_fdot2(as_h2(uB.x), ONE0, a0, false);
        a1 = __builtin_amdgcn_fdot2(as_h2(uB.x), ONE1, a1, false);
        a2 = __builtin_amdgcn_fdot2(as_h2(uB.y), ONE0, a2, false);
        a3 = __builtin_amdgcn_fdot2(as_h2(uB.y), ONE1, a3, false);
#else
        a0 += bf2f_lo(uA.x) + bf2f_lo(uB.x);
        a1 += bf2f_hi(uA.x) + bf2f_hi(uB.x);
        a2 += bf2f_lo(uA.y) + bf2f_lo(uB.y);
        a3 += bf2f_hi(uA.y) + bf2f_hi(uB.y);
#endif
    }
    for (; i < e; i += 4) {
        int idx = i + g;
        bool valid = idx < e;
        int s = srcSorted[valid ? idx : i];
        uint2 u = ((const uint2*)(p + (size_t)s * 32))[lf];
        float w = valid ? 1.f : 0.f;
#if USE_FDOT2
        h2 wv = {(_Float16)w, (_Float16)0.0f};
        h2 wv2 = {(_Float16)0.0f, (_Float16)w};
        a0 = __builtin_amdgcn_fdot2(as_h2(u.x), wv, a0, false);
        a1 = __builtin_amdgcn_fdot2(as_h2(u.x), wv2, a1, false);
        a2 = __builtin_amdgcn_fdot2(as_h2(u.y), wv, a2, false);
        a3 = __builtin_amdgcn_fdot2(as_h2(u.y), wv2, a3, false);
#else
        a0 = fmaf(bf2f_lo(u.x), w, a0);
        a1 = fmaf(bf2f_hi(u.x), w, a1);
        a2 = fmaf(bf2f_lo(u.y), w, a2);
        a3 = fmaf(bf2f_hi(u.y), w, a3);
#endif
    }
    a0 += __shfl_down(a0, 32); a1 += __shfl_down(a1, 32);
    a2 += __shfl_down(a2, 32); a3 += __shfl_down(a3, 32);
    a0 += __shfl_down(a0, 16); a1 += __shfl_down(a1, 16);
    a2 += __shfl_down(a2, 16); a3 += __shfl_down(a3, 16);
    if (lane < 16) {
        float inv = 1.0f / (float)max(e - b, 1);
        f32x4 qv = ((const f32x4*)(q + (size_t)node * 64))[lf];
        f32x4 o;
        o.x = 1.0f / (1.0f + __expf(-(a0 * inv + qv.x)));
        o.y = 1.0f / (1.0f + __expf(-(a1 * inv + qv.y)));
        o.z = 1.0f / (1.0f + __expf(-(a2 * inv + qv.z)));
        o.w = 1.0f / (1.0f + __expf(-(a3 * inv + qv.w)));
        ((f32x4*)(out + (size_t)node * 64))[lf] = o;
    }
}

// ---------------- launch ----------------

extern "C" void kernel_launch(void* const* d_in, const int* in_sizes, int n_in,
                              void* d_out, int out_size, void* d_ws, size_t ws_size,
                              hipStream_t stream) {
    const float* x   = (const float*)d_in[0];
    const int*   ei  = (const int*)d_in[1];
    const float* Wl1 = (const float*)d_in[2];
    const float* bl1 = (const float*)d_in[3];
    const float* Wr1 = (const float*)d_in[4];
    const float* Wl2 = (const float*)d_in[5];
    const float* bl2 = (const float*)d_in[6];
    const float* Wr2 = (const float*)d_in[7];
    float* out = (float*)d_out;

    const int* src = ei;
    const int* dst = ei + N_EDGES;

    char* ws = (char*)d_ws;
    size_t off = 0;
    auto carve = [&](size_t bytes) -> void* {
        void* ptr = ws + off;
        off = (off + bytes + 255) & ~(size_t)255;
        return ptr;
    };
    int* rowStart     = (int*)carve((N_NODES + 1) * sizeof(int));
    int* bucketCursor = (int*)carve(NB_BUCKETS * sizeof(int));
    unsigned* bucketData = (unsigned*)carve((size_t)NB_BUCKETS * BUCKET_CAP * sizeof(unsigned));
    int* srcSorted    = (int*)carve(N_EDGES * sizeof(int));
    unsigned* xb      = (unsigned*)carve((size_t)N_NODES * 64 * sizeof(unsigned));   // bf16 x
    unsigned* xq      = (unsigned*)carve((size_t)N_NODES * 32 * sizeof(unsigned));   // fp8 x
    unsigned* meanb   = (unsigned*)carve((size_t)N_NODES * 64 * sizeof(unsigned));
    unsigned short* p = (unsigned short*)carve((size_t)N_NODES * 64 * sizeof(short)); // fp16/bf16
    unsigned short* B1 = (unsigned short*)carve(256 * 128 * sizeof(short));
    unsigned short* B2 = (unsigned short*)carve(128 * 128 * sizeof(short));
    float* q = (float*)xb;   // overlay: q[row] exactly replaces xb[row] after that row's stage-1 reads

    // K1: fused setup
    hipMemsetAsync(bucketCursor, 0, NB_BUCKETS * sizeof(int), stream);
    setup_fused<<<NBLK_SCATTER + NBLK_CONVERT + NBLK_PREPB, 256, 0, stream>>>(
        src, dst, bucketCursor, bucketData, x, xb, xq, Wl1, Wr1, Wl2, Wr2, B1, B2);

    // K2: CSR
    bucket_to_csr<<<NB_BUCKETS, 256, 0, stream>>>(bucketData, bucketCursor, rowStart, srcSorted);

    // K3: layer-1 aggregation
    agg1_kernel<<<(N_NODES + 3) / 4, 256, 0, stream>>>(xq, rowStart, srcSorted, meanb);

    // K4: fused GEMMs (h in LDS only)
    gemm12_kernel<<<(N_NODES + 127) / 128, 256, 0, stream>>>(
        (const unsigned short*)meanb, (const unsigned short*)xb, B1, B2, bl1, bl2, p, q);

    // K5: layer-2 aggregation + sigmoid
    agg2_kernel<<<(N_NODES + 3) / 4, 256, 0, stream>>>((const unsigned*)p, q,
                                                       rowStart, srcSorted, out);
}

// Round 7
// 305.476 us; speedup vs baseline: 2.4494x; 1.0302x over previous
//
#include <hip/hip_runtime.h>
#include <math.h>

#define N_NODES 100000
#define N_EDGES 1600000
#define D_IN    128
#define HIDDEN  128
#define D_OUT   64

// ---- bucketed counting sort params ----
#define BUCKET_SHIFT 8
#define NB_BUCKETS ((N_NODES + 255) / 256)   // 391
#define BUCKET_CAP 6144
#define EPT 32
#define EPB (256 * EPT)                      // 8192
#define NBLK_SCATTER ((N_EDGES + EPB - 1) / EPB)   // 196
#define NBLK_CONVERT ((N_NODES * 32 + 255) / 256)  // 12500
#define NBLK_PREPB   ((256 * 128 + 128 * 128 + 255) / 256)  // 192

typedef short bf16x8 __attribute__((ext_vector_type(8)));
typedef float f32x4  __attribute__((ext_vector_type(4)));
typedef float f32x2  __attribute__((ext_vector_type(2)));
typedef _Float16 h2 __attribute__((ext_vector_type(2)));

#if defined(__has_builtin)
# if __has_builtin(__builtin_amdgcn_fdot2)
#  define USE_FDOT2 1
# endif
#endif
#ifndef USE_FDOT2
# define USE_FDOT2 0
#endif

__device__ __forceinline__ unsigned short f2bf(float f) {
    union { float f; unsigned u; } v; v.f = f;
    unsigned r = v.u + 0x7FFF + ((v.u >> 16) & 1);   // RNE
    return (unsigned short)(r >> 16);
}
__device__ __forceinline__ float bf2f_lo(unsigned u) {
    union { unsigned u; float f; } v; v.u = u << 16; return v.f;
}
__device__ __forceinline__ float bf2f_hi(unsigned u) {
    union { unsigned u; float f; } v; v.u = u & 0xFFFF0000u; return v.f;
}
__device__ __forceinline__ h2 as_h2(unsigned u) {
    union { unsigned u; h2 h; } c; c.u = u; return c.h;
}
__device__ __forceinline__ unsigned short f2h_bits(float f) {
    union { _Float16 h; unsigned short s; } c; c.h = (_Float16)f; return c.s;
}

// ---------------- K1: fused setup (scatter | convert | prep_b) ----------------

__global__ __launch_bounds__(256) void setup_fused(
    const int* __restrict__ src, const int* __restrict__ dst,
    int* __restrict__ bucketCursor, unsigned* __restrict__ bucketData,
    const float* __restrict__ x, unsigned* __restrict__ xb, unsigned* __restrict__ xq,
    const float* __restrict__ Wl1, const float* __restrict__ Wr1,
    const float* __restrict__ Wl2, const float* __restrict__ Wr2,
    unsigned short* __restrict__ B1, unsigned short* __restrict__ B2)
{
    __shared__ int cnt[NB_BUCKETS];
    __shared__ int base[NB_BUCKETS];
    int bid = blockIdx.x;
    int t = threadIdx.x;

    if (bid < NBLK_SCATTER) {
        for (int i = t; i < NB_BUCKETS; i += 256) cnt[i] = 0;
        __syncthreads();
        int start = bid * EPB;
#pragma unroll 4
        for (int j = 0; j < EPT; ++j) {
            int i = start + j * 256 + t;
            if (i < N_EDGES) atomicAdd(&cnt[dst[i] >> BUCKET_SHIFT], 1);
        }
        __syncthreads();
        for (int i = t; i < NB_BUCKETS; i += 256) {
            int c = cnt[i];
            base[i] = (c > 0) ? atomicAdd(&bucketCursor[i], c) : 0;
            cnt[i] = 0;
        }
        __syncthreads();
#pragma unroll 4
        for (int j = 0; j < EPT; ++j) {
            int i = start + j * 256 + t;
            if (i < N_EDGES) {
                int d = dst[i];
                int b = d >> BUCKET_SHIFT;
                int r = atomicAdd(&cnt[b], 1);
                int pos = base[b] + r;
                if (pos < BUCKET_CAP)
                    bucketData[(size_t)b * BUCKET_CAP + pos] =
                        ((unsigned)(d & 255) << 17) | (unsigned)src[i];
            }
        }
    } else if (bid < NBLK_SCATTER + NBLK_CONVERT) {
        long long g = (long long)(bid - NBLK_SCATTER) * 256 + t;
        if (g < (long long)N_NODES * 32) {
            float4 v = ((const float4*)x)[g];
            unsigned u0 = (unsigned)f2bf(v.x) | ((unsigned)f2bf(v.y) << 16);
            unsigned u1 = (unsigned)f2bf(v.z) | ((unsigned)f2bf(v.w) << 16);
            ((uint2*)xb)[g] = make_uint2(u0, u1);
            int q = 0;
            q = __builtin_amdgcn_cvt_pk_fp8_f32(v.x, v.y, q, false);
            q = __builtin_amdgcn_cvt_pk_fp8_f32(v.z, v.w, q, true);
            xq[g] = (unsigned)q;
        }
    } else {
        int e = (bid - NBLK_SCATTER - NBLK_CONVERT) * 256 + t;
        if (e < 256 * 128) {
            int k = e >> 7, n = e & 127;
            float w = (k < 128) ? Wl1[k * 128 + n] : Wr1[(k - 128) * 128 + n];
            int kstep = k >> 5, quad = (k >> 3) & 3, j = k & 7;
            int lane = quad * 16 + (n & 15), ntile = n >> 4;
            B1[((kstep * 8 + ntile) * 64 + lane) * 8 + j] = f2bf(w);
        } else if (e < 256 * 128 + 128 * 128) {
            int e2 = e - 256 * 128;
            int k = e2 >> 7, n = e2 & 127;
            float w = (n < 64) ? Wl2[k * 64 + n] : Wr2[k * 64 + (n - 64)];
            int kstep = k >> 5, quad = (k >> 3) & 3, j = k & 7;
            int lane = quad * 16 + (n & 15), ntile = n >> 4;
            B2[((kstep * 8 + ntile) * 64 + lane) * 8 + j] = f2bf(w);
        }
    }
}

// ---------------- K2: bucket -> CSR (self-scanning) ----------------

__global__ __launch_bounds__(256) void bucket_to_csr(
    const unsigned* __restrict__ bucketData, const int* __restrict__ bucketCursor,
    int* __restrict__ rowStart, int* __restrict__ srcSorted)
{
    __shared__ unsigned ent[BUCKET_CAP];
    __shared__ int hcnt[256];
    __shared__ int excl[256];
    __shared__ int ss[256];
    __shared__ int red[256];
    int b = blockIdx.x;
    int t = threadIdx.x;

    int partial = 0;
    for (int i = t; i < NB_BUCKETS; i += 256) {
        int c = bucketCursor[i];
        if (i < b) partial += c;
    }
    red[t] = partial;
    __syncthreads();
    for (int off = 128; off > 0; off >>= 1) {
        if (t < off) red[t] += red[t + off];
        __syncthreads();
    }
    int gbase = red[0];
    int n = bucketCursor[b];
    if (b == NB_BUCKETS - 1 && t == 0) rowStart[N_NODES] = gbase + n;
    if (n > BUCKET_CAP) n = BUCKET_CAP;

    hcnt[t] = 0;
    __syncthreads();
    for (int i = t; i < n; i += 256) {
        unsigned v = bucketData[(size_t)b * BUCKET_CAP + i];
        ent[i] = v;
        atomicAdd(&hcnt[v >> 17], 1);
    }
    __syncthreads();
    int myc = hcnt[t];
    ss[t] = myc;
    __syncthreads();
    for (int off = 1; off < 256; off <<= 1) {
        int tmp = (t >= off) ? ss[t - off] : 0;
        __syncthreads();
        ss[t] += tmp;
        __syncthreads();
    }
    excl[t] = ss[t] - myc;
    int node = b * 256 + t;
    if (node < N_NODES) rowStart[node] = gbase + excl[t];
    hcnt[t] = 0;
    __syncthreads();
    for (int i = t; i < n; i += 256) {
        unsigned v = ent[i];
        int d = v >> 17;
        int r = atomicAdd(&hcnt[d], 1);
        srcSorted[gbase + excl[d] + r] = (int)(v & 0x1FFFF);
    }
}

// ---------------- K3: agg1 (fp8 gather, 16 lanes/edge, up to 16 edges in flight) ----------------

__global__ void agg1_kernel(const unsigned* __restrict__ xq, const int* __restrict__ rowStart,
                            const int* __restrict__ srcSorted, unsigned* __restrict__ meanb) {
    int wave = threadIdx.x >> 6;
    int lane = threadIdx.x & 63;
    int node = blockIdx.x * 4 + wave;
    if (node >= N_NODES) return;
    int b = rowStart[node], e = rowStart[node + 1];
    int g  = lane >> 4;
    int lf = lane & 15;
    float a0=0.f,a1=0.f,a2=0.f,a3=0.f,a4=0.f,a5=0.f,a6=0.f,a7=0.f;
    int i = b;
    for (; i + 16 <= e; i += 16) {
        int sA = srcSorted[i + g];
        int sB = srcSorted[i + 4 + g];
        int sC = srcSorted[i + 8 + g];
        int sD = srcSorted[i + 12 + g];
        uint2 uA = ((const uint2*)(xq + (size_t)sA * 32))[lf];
        uint2 uB = ((const uint2*)(xq + (size_t)sB * 32))[lf];
        uint2 uC = ((const uint2*)(xq + (size_t)sC * 32))[lf];
        uint2 uD = ((const uint2*)(xq + (size_t)sD * 32))[lf];
        f32x2 v;
        v = __builtin_amdgcn_cvt_pk_f32_fp8(uA.x, false); a0 += v.x; a1 += v.y;
        v = __builtin_amdgcn_cvt_pk_f32_fp8(uA.x, true);  a2 += v.x; a3 += v.y;
        v = __builtin_amdgcn_cvt_pk_f32_fp8(uA.y, false); a4 += v.x; a5 += v.y;
        v = __builtin_amdgcn_cvt_pk_f32_fp8(uA.y, true);  a6 += v.x; a7 += v.y;
        v = __builtin_amdgcn_cvt_pk_f32_fp8(uB.x, false); a0 += v.x; a1 += v.y;
        v = __builtin_amdgcn_cvt_pk_f32_fp8(uB.x, true);  a2 += v.x; a3 += v.y;
        v = __builtin_amdgcn_cvt_pk_f32_fp8(uB.y, false); a4 += v.x; a5 += v.y;
        v = __builtin_amdgcn_cvt_pk_f32_fp8(uB.y, true);  a6 += v.x; a7 += v.y;
        v = __builtin_amdgcn_cvt_pk_f32_fp8(uC.x, false); a0 += v.x; a1 += v.y;
        v = __builtin_amdgcn_cvt_pk_f32_fp8(uC.x, true);  a2 += v.x; a3 += v.y;
        v = __builtin_amdgcn_cvt_pk_f32_fp8(uC.y, false); a4 += v.x; a5 += v.y;
        v = __builtin_amdgcn_cvt_pk_f32_fp8(uC.y, true);  a6 += v.x; a7 += v.y;
        v = __builtin_amdgcn_cvt_pk_f32_fp8(uD.x, false); a0 += v.x; a1 += v.y;
        v = __builtin_amdgcn_cvt_pk_f32_fp8(uD.x, true);  a2 += v.x; a3 += v.y;
        v = __builtin_amdgcn_cvt_pk_f32_fp8(uD.y, false); a4 += v.x; a5 += v.y;
        v = __builtin_amdgcn_cvt_pk_f32_fp8(uD.y, true);  a6 += v.x; a7 += v.y;
    }
    for (; i + 8 <= e; i += 8) {
        int sA = srcSorted[i + g];
        int sB = srcSorted[i + 4 + g];
        uint2 uA = ((const uint2*)(xq + (size_t)sA * 32))[lf];
        uint2 uB = ((const uint2*)(xq + (size_t)sB * 32))[lf];
        f32x2 v;
        v = __builtin_amdgcn_cvt_pk_f32_fp8(uA.x, false); a0 += v.x; a1 += v.y;
        v = __builtin_amdgcn_cvt_pk_f32_fp8(uA.x, true);  a2 += v.x; a3 += v.y;
        v = __builtin_amdgcn_cvt_pk_f32_fp8(uA.y, false); a4 += v.x; a5 += v.y;
        v = __builtin_amdgcn_cvt_pk_f32_fp8(uA.y, true);  a6 += v.x; a7 += v.y;
        v = __builtin_amdgcn_cvt_pk_f32_fp8(uB.x, false); a0 += v.x; a1 += v.y;
        v = __builtin_amdgcn_cvt_pk_f32_fp8(uB.x, true);  a2 += v.x; a3 += v.y;
        v = __builtin_amdgcn_cvt_pk_f32_fp8(uB.y, false); a4 += v.x; a5 += v.y;
        v = __builtin_amdgcn_cvt_pk_f32_fp8(uB.y, true);  a6 += v.x; a7 += v.y;
    }
    for (; i < e; i += 4) {
        int idx = i + g;
        bool valid = idx < e;
        int s = srcSorted[valid ? idx : i];
        uint2 u = ((const uint2*)(xq + (size_t)s * 32))[lf];
        float w = valid ? 1.f : 0.f;
        f32x2 lx = __builtin_amdgcn_cvt_pk_f32_fp8(u.x, false);
        f32x2 hx = __builtin_amdgcn_cvt_pk_f32_fp8(u.x, true);
        f32x2 ly = __builtin_amdgcn_cvt_pk_f32_fp8(u.y, false);
        f32x2 hy = __builtin_amdgcn_cvt_pk_f32_fp8(u.y, true);
        a0 = fmaf(lx.x, w, a0); a1 = fmaf(lx.y, w, a1);
        a2 = fmaf(hx.x, w, a2); a3 = fmaf(hx.y, w, a3);
        a4 = fmaf(ly.x, w, a4); a5 = fmaf(ly.y, w, a5);
        a6 = fmaf(hy.x, w, a6); a7 = fmaf(hy.y, w, a7);
    }
    a0 += __shfl_down(a0, 32); a1 += __shfl_down(a1, 32);
    a2 += __shfl_down(a2, 32); a3 += __shfl_down(a3, 32);
    a4 += __shfl_down(a4, 32); a5 += __shfl_down(a5, 32);
    a6 += __shfl_down(a6, 32); a7 += __shfl_down(a7, 32);
    a0 += __shfl_down(a0, 16); a1 += __shfl_down(a1, 16);
    a2 += __shfl_down(a2, 16); a3 += __shfl_down(a3, 16);
    a4 += __shfl_down(a4, 16); a5 += __shfl_down(a5, 16);
    a6 += __shfl_down(a6, 16); a7 += __shfl_down(a7, 16);
    if (lane < 16) {
        float inv = 1.0f / (float)max(e - b, 1);
        uint4 o;
        o.x = (unsigned)f2bf(a0 * inv) | ((unsigned)f2bf(a1 * inv) << 16);
        o.y = (unsigned)f2bf(a2 * inv) | ((unsigned)f2bf(a3 * inv) << 16);
        o.z = (unsigned)f2bf(a4 * inv) | ((unsigned)f2bf(a5 * inv) << 16);
        o.w = (unsigned)f2bf(a6 * inv) | ((unsigned)f2bf(a7 * inv) << 16);
        ((uint4*)(meanb + (size_t)node * 64))[lf] = o;
    }
}

// ---------------- K4: fused GEMM with B1/B2 staged in LDS ----------------
#define HSTRIDE 136   // shorts

__global__ __launch_bounds__(256) void gemm12_kernel(
    const unsigned short* __restrict__ meanb, const unsigned short* __restrict__ xb,
    const unsigned short* __restrict__ B1f, const unsigned short* __restrict__ B2f,
    const float* __restrict__ bl1, const float* __restrict__ bl2,
    unsigned short* __restrict__ p, float* __restrict__ q)
{
    __shared__ unsigned short hTile[128 * HSTRIDE];   // 34,816 B
    __shared__ int ldsB1[16384];                      // 65,536 B
    __shared__ int ldsB2[8192];                       // 32,768 B
    int tid = threadIdx.x;
    for (int i = tid; i < 4096; i += 256)
        ((int4*)ldsB1)[i] = ((const int4*)B1f)[i];
    for (int i = tid; i < 2048; i += 256)
        ((int4*)ldsB2)[i] = ((const int4*)B2f)[i];
    __syncthreads();

    int lane = tid & 63;
    int waveId = tid >> 6;
    int m = lane & 15, quad = lane >> 4;
    int rowBase = blockIdx.x * 128 + waveId * 32;
    int arow0 = rowBase + m;
    int arow1 = rowBase + 16 + m;
    bool ok0 = arow0 < N_NODES, ok1 = arow1 < N_NODES;

    const bf16x8* B1v = (const bf16x8*)ldsB1;
    const bf16x8* B2v = (const bf16x8*)ldsB2;

    // ---- stage 1: h = relu([meanb|xb] @ B1 + bl1) ----
    f32x4 acc[2][8];
#pragma unroll
    for (int s = 0; s < 2; ++s)
#pragma unroll
        for (int t = 0; t < 8; ++t) acc[s][t] = (f32x4){0.f, 0.f, 0.f, 0.f};

#pragma unroll
    for (int kstep = 0; kstep < 8; ++kstep) {
        int kglob = kstep * 32 + quad * 8;
        bf16x8 af0 = (bf16x8)(short)0, af1 = (bf16x8)(short)0;
        const unsigned short* basePtr;
        int koff;
        if (kglob < 128) { basePtr = meanb; koff = kglob; }
        else             { basePtr = xb;    koff = kglob - 128; }
        if (ok0) af0 = *(const bf16x8*)(basePtr + (size_t)arow0 * 128 + koff);
        if (ok1) af1 = *(const bf16x8*)(basePtr + (size_t)arow1 * 128 + koff);
#pragma unroll
        for (int nt = 0; nt < 8; ++nt) {
            bf16x8 bfrag = B1v[(kstep * 8 + nt) * 64 + lane];
            acc[0][nt] = __builtin_amdgcn_mfma_f32_16x16x32_bf16(af0, bfrag, acc[0][nt], 0, 0, 0);
            acc[1][nt] = __builtin_amdgcn_mfma_f32_16x16x32_bf16(af1, bfrag, acc[1][nt], 0, 0, 0);
        }
    }

    // epilogue 1 -> per-wave LDS region (no cross-wave barrier needed)
#pragma unroll
    for (int s = 0; s < 2; ++s)
#pragma unroll
        for (int nt = 0; nt < 8; ++nt) {
            int col = nt * 16 + m;
            float bias = bl1[col];
#pragma unroll
            for (int r = 0; r < 4; ++r) {
                int rowLocal = waveId * 32 + s * 16 + quad * 4 + r;
                float v = fmaxf(acc[s][nt][r] + bias, 0.f);
                hTile[rowLocal * HSTRIDE + col] = f2bf(v);
            }
        }

    // ---- stage 2: [p|q] = h @ B2 ----
    f32x4 acc2[2][8];
#pragma unroll
    for (int s = 0; s < 2; ++s)
#pragma unroll
        for (int t = 0; t < 8; ++t) acc2[s][t] = (f32x4){0.f, 0.f, 0.f, 0.f};

#pragma unroll
    for (int kstep = 0; kstep < 4; ++kstep) {
        int k0 = kstep * 32 + quad * 8;
        bf16x8 af0 = *(const bf16x8*)&hTile[(waveId * 32 + m) * HSTRIDE + k0];
        bf16x8 af1 = *(const bf16x8*)&hTile[(waveId * 32 + 16 + m) * HSTRIDE + k0];
#pragma unroll
        for (int nt = 0; nt < 8; ++nt) {
            bf16x8 bfrag = B2v[(kstep * 8 + nt) * 64 + lane];
            acc2[0][nt] = __builtin_amdgcn_mfma_f32_16x16x32_bf16(af0, bfrag, acc2[0][nt], 0, 0, 0);
            acc2[1][nt] = __builtin_amdgcn_mfma_f32_16x16x32_bf16(af1, bfrag, acc2[1][nt], 0, 0, 0);
        }
    }

#pragma unroll
    for (int s = 0; s < 2; ++s)
#pragma unroll
        for (int nt = 0; nt < 8; ++nt) {
            int col = nt * 16 + m;
            float bias = (col >= 64) ? bl2[col - 64] : 0.f;
#pragma unroll
            for (int r = 0; r < 4; ++r) {
                int row = rowBase + s * 16 + quad * 4 + r;
                if (row < N_NODES) {
                    float v = acc2[s][nt][r];
                    if (col < 64) {
#if USE_FDOT2
                        p[(size_t)row * 64 + col] = f2h_bits(v);
#else
                        p[(size_t)row * 64 + col] = f2bf(v);
#endif
                    } else {
                        q[(size_t)row * 64 + (col - 64)] = v + bias;
                    }
                }
            }
        }
}

// ---------------- K5: agg2 (p gather, 16 lanes/edge, up to 16 edges in flight) ----------------

__global__ void agg2_kernel(const unsigned* __restrict__ p, const float* __restrict__ q,
                            const int* __restrict__ rowStart, const int* __restrict__ srcSorted,
                            float* __restrict__ out) {
    int wave = threadIdx.x >> 6;
    int lane = threadIdx.x & 63;
    int node = blockIdx.x * 4 + wave;
    if (node >= N_NODES) return;
    int b = rowStart[node], e = rowStart[node + 1];
    int g  = lane >> 4;
    int lf = lane & 15;
    float a0=0.f,a1=0.f,a2=0.f,a3=0.f;
#if USE_FDOT2
    const h2 ONE0 = {(_Float16)1.0f, (_Float16)0.0f};
    const h2 ONE1 = {(_Float16)0.0f, (_Float16)1.0f};
#endif
    int i = b;
    for (; i + 16 <= e; i += 16) {
        int sA = srcSorted[i + g];
        int sB = srcSorted[i + 4 + g];
        int sC = srcSorted[i + 8 + g];
        int sD = srcSorted[i + 12 + g];
        uint2 uA = ((const uint2*)(p + (size_t)sA * 32))[lf];
        uint2 uB = ((const uint2*)(p + (size_t)sB * 32))[lf];
        uint2 uC = ((const uint2*)(p + (size_t)sC * 32))[lf];
        uint2 uD = ((const uint2*)(p + (size_t)sD * 32))[lf];
#if USE_FDOT2
        a0 = __builtin_amdgcn_fdot2(as_h2(uA.x), ONE0, a0, false);
        a1 = __builtin_amdgcn_fdot2(as_h2(uA.x), ONE1, a1, false);
        a2 = __builtin_amdgcn_fdot2(as_h2(uA.y), ONE0, a2, false);
        a3 = __builtin_amdgcn_fdot2(as_h2(uA.y), ONE1, a3, false);
        a0 = __builtin_amdgcn_fdot2(as_h2(uB.x), ONE0, a0, false);
        a1 = __builtin_amdgcn_fdot2(as_h2(uB.x), ONE1, a1, false);
        a2 = __builtin_amdgcn_fdot2(as_h2(uB.y), ONE0, a2, false);
        a3 = __builtin_amdgcn_fdot2(as_h2(uB.y), ONE1, a3, false);
        a0 = __builtin_amdgcn_fdot2(as_h2(uC.x), ONE0, a0, false);
        a1 = __builtin_amdgcn_fdot2(as_h2(uC.x), ONE1, a1, false);
        a2 = __builtin_amdgcn_fdot2(as_h2(uC.y), ONE0, a2, false);
        a3 = __builtin_amdgcn_fdot2(as_h2(uC.y), ONE1, a3, false);
        a0 = __builtin_amdgcn_fdot2(as_h2(uD.x), ONE0, a0, false);
        a1 = __builtin_amdgcn_fdot2(as_h2(uD.x), ONE1, a1, false);
        a2 = __builtin_amdgcn_fdot2(as_h2(uD.y), ONE0, a2, false);
        a3 = __builtin_amdgcn_fdot2(as_h2(uD.y), ONE1, a3, false);
#else
        a0 += bf2f_lo(uA.x) + bf2f_lo(uB.x) + bf2f_lo(uC.x) + bf2f_lo(uD.x);
        a1 += bf2f_hi(uA.x) + bf2f_hi(uB.x) + bf2f_hi(uC.x) + bf2f_hi(uD.x);
        a2 += bf2f_lo(uA.y) + bf2f_lo(uB.y) + bf2f_lo(uC.y) + bf2f_lo(uD.y);
        a3 += bf2f_hi(uA.y) + bf2f_hi(uB.y) + bf2f_hi(uC.y) + bf2f_hi(uD.y);
#endif
    }
    for (; i + 8 <= e; i += 8) {
        int sA = srcSorted[i + g];
        int sB = srcSorted[i + 4 + g];
        uint2 uA = ((const uint2*)(p + (size_t)sA * 32))[lf];
        uint2 uB = ((const uint2*)(p + (size_t)sB * 32))[lf];
#if USE_FDOT2
        a0 = __builtin_amdgcn_fdot2(as_h2(uA.x), ONE0, a0, false);
        a1 = __builtin_amdgcn_fdot2(as_h2(uA.x), ONE1, a1, false);
        a2 = __builtin_amdgcn_fdot2(as_h2(uA.y), ONE0, a2, false);
        a3 = __builtin_amdgcn_fdot2(as_h2(uA.y), ONE1, a3, false);
        a0 = __builtin_amdgcn_fdot2(as_h2(uB.x), ONE0, a0, false);
        a1 = __builtin_amdgcn_fdot2(as_h2(uB.x), ONE1, a1, false);
        a2 = __builtin_amdgcn_fdot2(as_h2(uB.y), ONE0, a2, false);
        a3 = __builtin_amdgcn_fdot2(as_h2(uB.y), ONE1, a3, false);
#else
        a0 += bf2f_lo(uA.x) + bf2f_lo(uB.x);
        a1 += bf2f_hi(uA.x) + bf2f_hi(uB.x);
        a2 += bf2f_lo(uA.y) + bf2f_lo(uB.y);
        a3 += bf2f_hi(uA.y) + bf2f_hi(uB.y);
#endif
    }
    for (; i < e; i += 4) {
        int idx = i + g;
        bool valid = idx < e;
        int s = srcSorted[valid ? idx : i];
        uint2 u = ((const uint2*)(p + (size_t)s * 32))[lf];
        float w = valid ? 1.f : 0.f;
#if USE_FDOT2
        h2 wv = {(_Float16)w, (_Float16)0.0f};
        h2 wv2 = {(_Float16)0.0f, (_Float16)w};
        a0 = __builtin_amdgcn_fdot2(as_h2(u.x), wv, a0, false);
        a1 = __builtin_amdgcn_fdot2(as_h2(u.x), wv2, a1, false);
        a2 = __builtin_amdgcn_fdot2(as_h2(u.y), wv, a2, false);
        a3 = __builtin_amdgcn_fdot2(as_h2(u.y), wv2, a3, false);
#else
        a0 = fmaf(bf2f_lo(u.x), w, a0);
        a1 = fmaf(bf2f_hi(u.x), w, a1);
        a2 = fmaf(bf2f_lo(u.y), w, a2);
        a3 = fmaf(bf2f_hi(u.y), w, a3);
#endif
    }
    a0 += __shfl_down(a0, 32); a1 += __shfl_down(a1, 32);
    a2 += __shfl_down(a2, 32); a3 += __shfl_down(a3, 32);
    a0 += __shfl_down(a0, 16); a1 += __shfl_down(a1, 16);
    a2 += __shfl_down(a2, 16); a3 += __shfl_down(a3, 16);
    if (lane < 16) {
        float inv = 1.0f / (float)max(e - b, 1);
        f32x4 qv = ((const f32x4*)(q + (size_t)node * 64))[lf];
        f32x4 o;
        o.x = 1.0f / (1.0f + __expf(-(a0 * inv + qv.x)));
        o.y = 1.0f / (1.0f + __expf(-(a1 * inv + qv.y)));
        o.z = 1.0f / (1.0f + __expf(-(a2 * inv + qv.z)));
        o.w = 1.0f / (1.0f + __expf(-(a3 * inv + qv.w)));
        ((f32x4*)(out + (size_t)node * 64))[lf] = o;
    }
}

// ---------------- launch ----------------

extern "C" void kernel_launch(void* const* d_in, const int* in_sizes, int n_in,
                              void* d_out, int out_size, void* d_ws, size_t ws_size,
                              hipStream_t stream) {
    const float* x   = (const float*)d_in[0];
    const int*   ei  = (const int*)d_in[1];
    const float* Wl1 = (const float*)d_in[2];
    const float* bl1 = (const float*)d_in[3];
    const float* Wr1 = (const float*)d_in[4];
    const float* Wl2 = (const float*)d_in[5];
    const float* bl2 = (const float*)d_in[6];
    const float* Wr2 = (const float*)d_in[7];
    float* out = (float*)d_out;

    const int* src = ei;
    const int* dst = ei + N_EDGES;

    char* ws = (char*)d_ws;
    size_t off = 0;
    auto carve = [&](size_t bytes) -> void* {
        void* ptr = ws + off;
        off = (off + bytes + 255) & ~(size_t)255;
        return ptr;
    };
    int* rowStart     = (int*)carve((N_NODES + 1) * sizeof(int));
    int* bucketCursor = (int*)carve(NB_BUCKETS * sizeof(int));
    unsigned* bucketData = (unsigned*)carve((size_t)NB_BUCKETS * BUCKET_CAP * sizeof(unsigned));
    int* srcSorted    = (int*)carve(N_EDGES * sizeof(int));
    unsigned* xb      = (unsigned*)carve((size_t)N_NODES * 64 * sizeof(unsigned));   // bf16 x
    unsigned* xq      = (unsigned*)carve((size_t)N_NODES * 32 * sizeof(unsigned));   // fp8 x
    unsigned* meanb   = (unsigned*)carve((size_t)N_NODES * 64 * sizeof(unsigned));
    unsigned short* p = (unsigned short*)carve((size_t)N_NODES * 64 * sizeof(short)); // fp16/bf16
    unsigned short* B1 = (unsigned short*)carve(256 * 128 * sizeof(short));
    unsigned short* B2 = (unsigned short*)carve(128 * 128 * sizeof(short));
    float* q = (float*)xb;   // overlay: q[row] replaces xb[row] after stage-1 reads of that row

    // K1: fused setup
    hipMemsetAsync(bucketCursor, 0, NB_BUCKETS * sizeof(int), stream);
    setup_fused<<<NBLK_SCATTER + NBLK_CONVERT + NBLK_PREPB, 256, 0, stream>>>(
        src, dst, bucketCursor, bucketData, x, xb, xq, Wl1, Wr1, Wl2, Wr2, B1, B2);

    // K2: CSR
    bucket_to_csr<<<NB_BUCKETS, 256, 0, stream>>>(bucketData, bucketCursor, rowStart, srcSorted);

    // K3: layer-1 aggregation
    agg1_kernel<<<(N_NODES + 3) / 4, 256, 0, stream>>>(xq, rowStart, srcSorted, meanb);

    // K4: fused GEMMs (B1/B2 + h in LDS)
    gemm12_kernel<<<(N_NODES + 127) / 128, 256, 0, stream>>>(
        (const unsigned short*)meanb, (const unsigned short*)xb, B1, B2, bl1, bl2, p, q);

    // K5: layer-2 aggregation + sigmoid
    agg2_kernel<<<(N_NODES + 3) / 4, 256, 0, stream>>>((const unsigned*)p, q,
                                                       rowStart, srcSorted, out);
}

// Round 8
// 279.181 us; speedup vs baseline: 2.6801x; 1.0942x over previous
//
#include <hip/hip_runtime.h>
#include <math.h>

#define N_NODES 100000
#define N_EDGES 1600000
#define D_IN    128
#define HIDDEN  128
#define D_OUT   64

// ---- bucketed counting sort params ----
#define BUCKET_SHIFT 8
#define NB_BUCKETS ((N_NODES + 255) / 256)   // 391
#define BUCKET_CAP 6144
#define EPT 16
#define EPB (256 * EPT)                      // 4096
#define NBLK_SCATTER ((N_EDGES + EPB - 1) / EPB)        // 391
#define NBLK_CONVERT ((N_NODES * 16 + 255) / 256)       // 6250 (2 float4/thread)
#define NBLK_PREPB   ((256 * 128 + 128 * 128 + 255) / 256)  // 192

typedef short bf16x8 __attribute__((ext_vector_type(8)));
typedef float f32x4  __attribute__((ext_vector_type(4)));
typedef float f32x2  __attribute__((ext_vector_type(2)));
typedef _Float16 h2 __attribute__((ext_vector_type(2)));

#if defined(__has_builtin)
# if __has_builtin(__builtin_amdgcn_fdot2)
#  define USE_FDOT2 1
# endif
#endif
#ifndef USE_FDOT2
# define USE_FDOT2 0
#endif

__device__ __forceinline__ unsigned short f2bf(float f) {
    union { float f; unsigned u; } v; v.f = f;
    unsigned r = v.u + 0x7FFF + ((v.u >> 16) & 1);   // RNE
    return (unsigned short)(r >> 16);
}
__device__ __forceinline__ float bf2f_lo(unsigned u) {
    union { unsigned u; float f; } v; v.u = u << 16; return v.f;
}
__device__ __forceinline__ float bf2f_hi(unsigned u) {
    union { unsigned u; float f; } v; v.u = u & 0xFFFF0000u; return v.f;
}
__device__ __forceinline__ h2 as_h2(unsigned u) {
    union { unsigned u; h2 h; } c; c.u = u; return c.h;
}
__device__ __forceinline__ unsigned short f2h_bits(float f) {
    union { _Float16 h; unsigned short s; } c; c.h = (_Float16)f; return c.s;
}

// ---------------- K1: fused setup (scatter | convert | prep_b) ----------------

__global__ __launch_bounds__(256) void setup_fused(
    const int* __restrict__ src, const int* __restrict__ dst,
    int* __restrict__ bucketCursor, unsigned* __restrict__ bucketData,
    const float* __restrict__ x, unsigned* __restrict__ xb, unsigned* __restrict__ xq,
    const float* __restrict__ Wl1, const float* __restrict__ Wr1,
    const float* __restrict__ Wl2, const float* __restrict__ Wr2,
    unsigned short* __restrict__ B1, unsigned short* __restrict__ B2)
{
    __shared__ int cnt[NB_BUCKETS];
    __shared__ int base[NB_BUCKETS];
    int bid = blockIdx.x;
    int t = threadIdx.x;

    if (bid < NBLK_SCATTER) {
        for (int i = t; i < NB_BUCKETS; i += 256) cnt[i] = 0;
        __syncthreads();
        int start = bid * EPB;
#pragma unroll 4
        for (int j = 0; j < EPT; ++j) {
            int i = start + j * 256 + t;
            if (i < N_EDGES) atomicAdd(&cnt[dst[i] >> BUCKET_SHIFT], 1);
        }
        __syncthreads();
        for (int i = t; i < NB_BUCKETS; i += 256) {
            int c = cnt[i];
            base[i] = (c > 0) ? atomicAdd(&bucketCursor[i], c) : 0;
            cnt[i] = 0;
        }
        __syncthreads();
#pragma unroll 4
        for (int j = 0; j < EPT; ++j) {
            int i = start + j * 256 + t;
            if (i < N_EDGES) {
                int d = dst[i];
                int b = d >> BUCKET_SHIFT;
                int r = atomicAdd(&cnt[b], 1);
                int pos = base[b] + r;
                if (pos < BUCKET_CAP)
                    bucketData[(size_t)b * BUCKET_CAP + pos] =
                        ((unsigned)(d & 255) << 17) | (unsigned)src[i];
            }
        }
    } else if (bid < NBLK_SCATTER + NBLK_CONVERT) {
        // 2 float4s per thread; uint4 write to xb, uint2 write to xq
        long long g = (long long)(bid - NBLK_SCATTER) * 256 + t;
        if (g < (long long)N_NODES * 16) {
            float4 v0 = ((const float4*)x)[g * 2];
            float4 v1 = ((const float4*)x)[g * 2 + 1];
            uint4 ob;
            ob.x = (unsigned)f2bf(v0.x) | ((unsigned)f2bf(v0.y) << 16);
            ob.y = (unsigned)f2bf(v0.z) | ((unsigned)f2bf(v0.w) << 16);
            ob.z = (unsigned)f2bf(v1.x) | ((unsigned)f2bf(v1.y) << 16);
            ob.w = (unsigned)f2bf(v1.z) | ((unsigned)f2bf(v1.w) << 16);
            ((uint4*)xb)[g] = ob;
            int q0 = 0, q1 = 0;
            q0 = __builtin_amdgcn_cvt_pk_fp8_f32(v0.x, v0.y, q0, false);
            q0 = __builtin_amdgcn_cvt_pk_fp8_f32(v0.z, v0.w, q0, true);
            q1 = __builtin_amdgcn_cvt_pk_fp8_f32(v1.x, v1.y, q1, false);
            q1 = __builtin_amdgcn_cvt_pk_fp8_f32(v1.z, v1.w, q1, true);
            ((uint2*)xq)[g] = make_uint2((unsigned)q0, (unsigned)q1);
        }
    } else {
        int e = (bid - NBLK_SCATTER - NBLK_CONVERT) * 256 + t;
        if (e < 256 * 128) {
            int k = e >> 7, n = e & 127;
            float w = (k < 128) ? Wl1[k * 128 + n] : Wr1[(k - 128) * 128 + n];
            int kstep = k >> 5, quad = (k >> 3) & 3, j = k & 7;
            int lane = quad * 16 + (n & 15), ntile = n >> 4;
            B1[((kstep * 8 + ntile) * 64 + lane) * 8 + j] = f2bf(w);
        } else if (e < 256 * 128 + 128 * 128) {
            int e2 = e - 256 * 128;
            int k = e2 >> 7, n = e2 & 127;
            float w = (n < 64) ? Wl2[k * 64 + n] : Wr2[k * 64 + (n - 64)];
            int kstep = k >> 5, quad = (k >> 3) & 3, j = k & 7;
            int lane = quad * 16 + (n & 15), ntile = n >> 4;
            B2[((kstep * 8 + ntile) * 64 + lane) * 8 + j] = f2bf(w);
        }
    }
}

// ---------------- K2: bucket -> CSR (self-scanning) ----------------

__global__ __launch_bounds__(256) void bucket_to_csr(
    const unsigned* __restrict__ bucketData, const int* __restrict__ bucketCursor,
    int* __restrict__ rowStart, int* __restrict__ srcSorted)
{
    __shared__ unsigned ent[BUCKET_CAP];
    __shared__ int hcnt[256];
    __shared__ int excl[256];
    __shared__ int ss[256];
    __shared__ int red[256];
    int b = blockIdx.x;
    int t = threadIdx.x;

    int partial = 0;
    for (int i = t; i < NB_BUCKETS; i += 256) {
        int c = bucketCursor[i];
        if (i < b) partial += c;
    }
    red[t] = partial;
    __syncthreads();
    for (int off = 128; off > 0; off >>= 1) {
        if (t < off) red[t] += red[t + off];
        __syncthreads();
    }
    int gbase = red[0];
    int n = bucketCursor[b];
    if (b == NB_BUCKETS - 1 && t == 0) rowStart[N_NODES] = gbase + n;
    if (n > BUCKET_CAP) n = BUCKET_CAP;

    hcnt[t] = 0;
    __syncthreads();
    for (int i = t; i < n; i += 256) {
        unsigned v = bucketData[(size_t)b * BUCKET_CAP + i];
        ent[i] = v;
        atomicAdd(&hcnt[v >> 17], 1);
    }
    __syncthreads();
    int myc = hcnt[t];
    ss[t] = myc;
    __syncthreads();
    for (int off = 1; off < 256; off <<= 1) {
        int tmp = (t >= off) ? ss[t - off] : 0;
        __syncthreads();
        ss[t] += tmp;
        __syncthreads();
    }
    excl[t] = ss[t] - myc;
    int node = b * 256 + t;
    if (node < N_NODES) rowStart[node] = gbase + excl[t];
    hcnt[t] = 0;
    __syncthreads();
    for (int i = t; i < n; i += 256) {
        unsigned v = ent[i];
        int d = v >> 17;
        int r = atomicAdd(&hcnt[d], 1);
        srcSorted[gbase + excl[d] + r] = (int)(v & 0x1FFFF);
    }
}

// ---------------- K3: agg1 (fp8 gather, 16 lanes/edge, up to 16 edges in flight) ----------------

__global__ void agg1_kernel(const unsigned* __restrict__ xq, const int* __restrict__ rowStart,
                            const int* __restrict__ srcSorted, unsigned* __restrict__ meanb) {
    int wave = threadIdx.x >> 6;
    int lane = threadIdx.x & 63;
    int node = blockIdx.x * 4 + wave;
    if (node >= N_NODES) return;
    int b = rowStart[node], e = rowStart[node + 1];
    int g  = lane >> 4;
    int lf = lane & 15;
    float a0=0.f,a1=0.f,a2=0.f,a3=0.f,a4=0.f,a5=0.f,a6=0.f,a7=0.f;
    int i = b;
    for (; i + 16 <= e; i += 16) {
        int sA = srcSorted[i + g];
        int sB = srcSorted[i + 4 + g];
        int sC = srcSorted[i + 8 + g];
        int sD = srcSorted[i + 12 + g];
        uint2 uA = ((const uint2*)(xq + (size_t)sA * 32))[lf];
        uint2 uB = ((const uint2*)(xq + (size_t)sB * 32))[lf];
        uint2 uC = ((const uint2*)(xq + (size_t)sC * 32))[lf];
        uint2 uD = ((const uint2*)(xq + (size_t)sD * 32))[lf];
        f32x2 v;
        v = __builtin_amdgcn_cvt_pk_f32_fp8(uA.x, false); a0 += v.x; a1 += v.y;
        v = __builtin_amdgcn_cvt_pk_f32_fp8(uA.x, true);  a2 += v.x; a3 += v.y;
        v = __builtin_amdgcn_cvt_pk_f32_fp8(uA.y, false); a4 += v.x; a5 += v.y;
        v = __builtin_amdgcn_cvt_pk_f32_fp8(uA.y, true);  a6 += v.x; a7 += v.y;
        v = __builtin_amdgcn_cvt_pk_f32_fp8(uB.x, false); a0 += v.x; a1 += v.y;
        v = __builtin_amdgcn_cvt_pk_f32_fp8(uB.x, true);  a2 += v.x; a3 += v.y;
        v = __builtin_amdgcn_cvt_pk_f32_fp8(uB.y, false); a4 += v.x; a5 += v.y;
        v = __builtin_amdgcn_cvt_pk_f32_fp8(uB.y, true);  a6 += v.x; a7 += v.y;
        v = __builtin_amdgcn_cvt_pk_f32_fp8(uC.x, false); a0 += v.x; a1 += v.y;
        v = __builtin_amdgcn_cvt_pk_f32_fp8(uC.x, true);  a2 += v.x; a3 += v.y;
        v = __builtin_amdgcn_cvt_pk_f32_fp8(uC.y, false); a4 += v.x; a5 += v.y;
        v = __builtin_amdgcn_cvt_pk_f32_fp8(uC.y, true);  a6 += v.x; a7 += v.y;
        v = __builtin_amdgcn_cvt_pk_f32_fp8(uD.x, false); a0 += v.x; a1 += v.y;
        v = __builtin_amdgcn_cvt_pk_f32_fp8(uD.x, true);  a2 += v.x; a3 += v.y;
        v = __builtin_amdgcn_cvt_pk_f32_fp8(uD.y, false); a4 += v.x; a5 += v.y;
        v = __builtin_amdgcn_cvt_pk_f32_fp8(uD.y, true);  a6 += v.x; a7 += v.y;
    }
    for (; i + 8 <= e; i += 8) {
        int sA = srcSorted[i + g];
        int sB = srcSorted[i + 4 + g];
        uint2 uA = ((const uint2*)(xq + (size_t)sA * 32))[lf];
        uint2 uB = ((const uint2*)(xq + (size_t)sB * 32))[lf];
        f32x2 v;
        v = __builtin_amdgcn_cvt_pk_f32_fp8(uA.x, false); a0 += v.x; a1 += v.y;
        v = __builtin_amdgcn_cvt_pk_f32_fp8(uA.x, true);  a2 += v.x; a3 += v.y;
        v = __builtin_amdgcn_cvt_pk_f32_fp8(uA.y, false); a4 += v.x; a5 += v.y;
        v = __builtin_amdgcn_cvt_pk_f32_fp8(uA.y, true);  a6 += v.x; a7 += v.y;
        v = __builtin_amdgcn_cvt_pk_f32_fp8(uB.x, false); a0 += v.x; a1 += v.y;
        v = __builtin_amdgcn_cvt_pk_f32_fp8(uB.x, true);  a2 += v.x; a3 += v.y;
        v = __builtin_amdgcn_cvt_pk_f32_fp8(uB.y, false); a4 += v.x; a5 += v.y;
        v = __builtin_amdgcn_cvt_pk_f32_fp8(uB.y, true);  a6 += v.x; a7 += v.y;
    }
    for (; i < e; i += 4) {
        int idx = i + g;
        bool valid = idx < e;
        int s = srcSorted[valid ? idx : i];
        uint2 u = ((const uint2*)(xq + (size_t)s * 32))[lf];
        float w = valid ? 1.f : 0.f;
        f32x2 lx = __builtin_amdgcn_cvt_pk_f32_fp8(u.x, false);
        f32x2 hx = __builtin_amdgcn_cvt_pk_f32_fp8(u.x, true);
        f32x2 ly = __builtin_amdgcn_cvt_pk_f32_fp8(u.y, false);
        f32x2 hy = __builtin_amdgcn_cvt_pk_f32_fp8(u.y, true);
        a0 = fmaf(lx.x, w, a0); a1 = fmaf(lx.y, w, a1);
        a2 = fmaf(hx.x, w, a2); a3 = fmaf(hx.y, w, a3);
        a4 = fmaf(ly.x, w, a4); a5 = fmaf(ly.y, w, a5);
        a6 = fmaf(hy.x, w, a6); a7 = fmaf(hy.y, w, a7);
    }
    a0 += __shfl_down(a0, 32); a1 += __shfl_down(a1, 32);
    a2 += __shfl_down(a2, 32); a3 += __shfl_down(a3, 32);
    a4 += __shfl_down(a4, 32); a5 += __shfl_down(a5, 32);
    a6 += __shfl_down(a6, 32); a7 += __shfl_down(a7, 32);
    a0 += __shfl_down(a0, 16); a1 += __shfl_down(a1, 16);
    a2 += __shfl_down(a2, 16); a3 += __shfl_down(a3, 16);
    a4 += __shfl_down(a4, 16); a5 += __shfl_down(a5, 16);
    a6 += __shfl_down(a6, 16); a7 += __shfl_down(a7, 16);
    if (lane < 16) {
        float inv = 1.0f / (float)max(e - b, 1);
        uint4 o;
        o.x = (unsigned)f2bf(a0 * inv) | ((unsigned)f2bf(a1 * inv) << 16);
        o.y = (unsigned)f2bf(a2 * inv) | ((unsigned)f2bf(a3 * inv) << 16);
        o.z = (unsigned)f2bf(a4 * inv) | ((unsigned)f2bf(a5 * inv) << 16);
        o.w = (unsigned)f2bf(a6 * inv) | ((unsigned)f2bf(a7 * inv) << 16);
        ((uint4*)(meanb + (size_t)node * 64))[lf] = o;
    }
}

// ---------------- K4: fused GEMM, 512 thr, 32 KB B ping-buffer (3 phases) ----------------
#define HSTRIDE 136   // shorts; 272 B rows (16B aligned), 2-way bank alias only

__global__ __launch_bounds__(512) void gemm12_kernel(
    const unsigned short* __restrict__ meanb, const unsigned short* __restrict__ xb,
    const unsigned short* __restrict__ B1f, const unsigned short* __restrict__ B2f,
    const float* __restrict__ bl1, const float* __restrict__ bl2,
    unsigned short* __restrict__ p, float* __restrict__ q)
{
    __shared__ unsigned short hTile[128 * HSTRIDE];   // 34,816 B
    __shared__ int ldsB[8192];                        // 32,768 B ping buffer
    int tid = threadIdx.x;
    int lane = tid & 63;
    int waveId = tid >> 6;            // 0..7
    int m = lane & 15, quad = lane >> 4;
    int rowBase = blockIdx.x * 128 + waveId * 16;
    int arow = rowBase + m;
    bool ok = arow < N_NODES;

    // Prefetch all A fragments (in flight during B staging)
    bf16x8 afM[4], afX[4];
#pragma unroll
    for (int ks = 0; ks < 4; ++ks) {
        int kglob = ks * 32 + quad * 8;
        afM[ks] = ok ? *(const bf16x8*)(meanb + (size_t)arow * 128 + kglob) : (bf16x8)(short)0;
        afX[ks] = ok ? *(const bf16x8*)(xb   + (size_t)arow * 128 + kglob) : (bf16x8)(short)0;
    }

    const bf16x8* Bv = (const bf16x8*)ldsB;
    f32x4 acc[8];
#pragma unroll
    for (int t = 0; t < 8; ++t) acc[t] = (f32x4){0.f, 0.f, 0.f, 0.f};

    // ---- phase A: B1 ksteps 0-3 (meanb half) ----
    for (int i = tid; i < 2048; i += 512)
        ((int4*)ldsB)[i] = ((const int4*)B1f)[i];
    __syncthreads();
#pragma unroll
    for (int ks = 0; ks < 4; ++ks)
#pragma unroll
        for (int nt = 0; nt < 8; ++nt)
            acc[nt] = __builtin_amdgcn_mfma_f32_16x16x32_bf16(
                afM[ks], Bv[(ks * 8 + nt) * 64 + lane], acc[nt], 0, 0, 0);
    __syncthreads();

    // ---- phase B: B1 ksteps 4-7 (xb half) ----
    for (int i = tid; i < 2048; i += 512)
        ((int4*)ldsB)[i] = ((const int4*)B1f)[2048 + i];
    __syncthreads();
#pragma unroll
    for (int ks = 0; ks < 4; ++ks)
#pragma unroll
        for (int nt = 0; nt < 8; ++nt)
            acc[nt] = __builtin_amdgcn_mfma_f32_16x16x32_bf16(
                afX[ks], Bv[(ks * 8 + nt) * 64 + lane], acc[nt], 0, 0, 0);
    __syncthreads();   // all waves done reading ldsB before B2 overwrite

    // epilogue 1 -> wave-local hTile rows [waveId*16, waveId*16+16)
#pragma unroll
    for (int nt = 0; nt < 8; ++nt) {
        int col = nt * 16 + m;
        float bias = bl1[col];
#pragma unroll
        for (int r = 0; r < 4; ++r) {
            int rowLocal = waveId * 16 + quad * 4 + r;
            float v = fmaxf(acc[nt][r] + bias, 0.f);
            hTile[rowLocal * HSTRIDE + col] = f2bf(v);
        }
    }

    // ---- phase C: B2 ----
    for (int i = tid; i < 2048; i += 512)
        ((int4*)ldsB)[i] = ((const int4*)B2f)[i];
    __syncthreads();

    f32x4 acc2[8];
#pragma unroll
    for (int t = 0; t < 8; ++t) acc2[t] = (f32x4){0.f, 0.f, 0.f, 0.f};
#pragma unroll
    for (int ks = 0; ks < 4; ++ks) {
        int k0 = ks * 32 + quad * 8;
        bf16x8 af = *(const bf16x8*)&hTile[(waveId * 16 + m) * HSTRIDE + k0];
#pragma unroll
        for (int nt = 0; nt < 8; ++nt)
            acc2[nt] = __builtin_amdgcn_mfma_f32_16x16x32_bf16(
                af, Bv[(ks * 8 + nt) * 64 + lane], acc2[nt], 0, 0, 0);
    }

#pragma unroll
    for (int nt = 0; nt < 8; ++nt) {
        int col = nt * 16 + m;
        float bias = (col >= 64) ? bl2[col - 64] : 0.f;
#pragma unroll
        for (int r = 0; r < 4; ++r) {
            int row = rowBase + quad * 4 + r;
            if (row < N_NODES) {
                float v = acc2[nt][r];
                if (col < 64) {
#if USE_FDOT2
                    p[(size_t)row * 64 + col] = f2h_bits(v);
#else
                    p[(size_t)row * 64 + col] = f2bf(v);
#endif
                } else {
                    q[(size_t)row * 64 + (col - 64)] = v + bias;
                }
            }
        }
    }
}

// ---------------- K5: agg2 (p gather, 16 lanes/edge, up to 16 edges in flight) ----------------

__global__ void agg2_kernel(const unsigned* __restrict__ p, const float* __restrict__ q,
                            const int* __restrict__ rowStart, const int* __restrict__ srcSorted,
                            float* __restrict__ out) {
    int wave = threadIdx.x >> 6;
    int lane = threadIdx.x & 63;
    int node = blockIdx.x * 4 + wave;
    if (node >= N_NODES) return;
    int b = rowStart[node], e = rowStart[node + 1];
    int g  = lane >> 4;
    int lf = lane & 15;
    float a0=0.f,a1=0.f,a2=0.f,a3=0.f;
#if USE_FDOT2
    const h2 ONE0 = {(_Float16)1.0f, (_Float16)0.0f};
    const h2 ONE1 = {(_Float16)0.0f, (_Float16)1.0f};
#endif
    int i = b;
    for (; i + 16 <= e; i += 16) {
        int sA = srcSorted[i + g];
        int sB = srcSorted[i + 4 + g];
        int sC = srcSorted[i + 8 + g];
        int sD = srcSorted[i + 12 + g];
        uint2 uA = ((const uint2*)(p + (size_t)sA * 32))[lf];
        uint2 uB = ((const uint2*)(p + (size_t)sB * 32))[lf];
        uint2 uC = ((const uint2*)(p + (size_t)sC * 32))[lf];
        uint2 uD = ((const uint2*)(p + (size_t)sD * 32))[lf];
#if USE_FDOT2
        a0 = __builtin_amdgcn_fdot2(as_h2(uA.x), ONE0, a0, false);
        a1 = __builtin_amdgcn_fdot2(as_h2(uA.x), ONE1, a1, false);
        a2 = __builtin_amdgcn_fdot2(as_h2(uA.y), ONE0, a2, false);
        a3 = __builtin_amdgcn_fdot2(as_h2(uA.y), ONE1, a3, false);
        a0 = __builtin_amdgcn_fdot2(as_h2(uB.x), ONE0, a0, false);
        a1 = __builtin_amdgcn_fdot2(as_h2(uB.x), ONE1, a1, false);
        a2 = __builtin_amdgcn_fdot2(as_h2(uB.y), ONE0, a2, false);
        a3 = __builtin_amdgcn_fdot2(as_h2(uB.y), ONE1, a3, false);
        a0 = __builtin_amdgcn_fdot2(as_h2(uC.x), ONE0, a0, false);
        a1 = __builtin_amdgcn_fdot2(as_h2(uC.x), ONE1, a1, false);
        a2 = __builtin_amdgcn_fdot2(as_h2(uC.y), ONE0, a2, false);
        a3 = __builtin_amdgcn_fdot2(as_h2(uC.y), ONE1, a3, false);
        a0 = __builtin_amdgcn_fdot2(as_h2(uD.x), ONE0, a0, false);
        a1 = __builtin_amdgcn_fdot2(as_h2(uD.x), ONE1, a1, false);
        a2 = __builtin_amdgcn_fdot2(as_h2(uD.y), ONE0, a2, false);
        a3 = __builtin_amdgcn_fdot2(as_h2(uD.y), ONE1, a3, false);
#else
        a0 += bf2f_lo(uA.x) + bf2f_lo(uB.x) + bf2f_lo(uC.x) + bf2f_lo(uD.x);
        a1 += bf2f_hi(uA.x) + bf2f_hi(uB.x) + bf2f_hi(uC.x) + bf2f_hi(uD.x);
        a2 += bf2f_lo(uA.y) + bf2f_lo(uB.y) + bf2f_lo(uC.y) + bf2f_lo(uD.y);
        a3 += bf2f_hi(uA.y) + bf2f_hi(uB.y) + bf2f_hi(uC.y) + bf2f_hi(uD.y);
#endif
    }
    for (; i + 8 <= e; i += 8) {
        int sA = srcSorted[i + g];
        int sB = srcSorted[i + 4 + g];
        uint2 uA = ((const uint2*)(p + (size_t)sA * 32))[lf];
        uint2 uB = ((const uint2*)(p + (size_t)sB * 32))[lf];
#if USE_FDOT2
        a0 = __builtin_amdgcn_fdot2(as_h2(uA.x), ONE0, a0, false);
        a1 = __builtin_amdgcn_fdot2(as_h2(uA.x), ONE1, a1, false);
        a2 = __builtin_amdgcn_fdot2(as_h2(uA.y), ONE0, a2, false);
        a3 = __builtin_amdgcn_fdot2(as_h2(uA.y), ONE1, a3, false);
        a0 = __builtin_amdgcn_fdot2(as_h2(uB.x), ONE0, a0, false);
        a1 = __builtin_amdgcn_fdot2(as_h2(uB.x), ONE1, a1, false);
        a2 = __builtin_amdgcn_fdot2(as_h2(uB.y), ONE0, a2, false);
        a3 = __builtin_amdgcn_fdot2(as_h2(uB.y), ONE1, a3, false);
#else
        a0 += bf2f_lo(uA.x) + bf2f_lo(uB.x);
        a1 += bf2f_hi(uA.x) + bf2f_hi(uB.x);
        a2 += bf2f_lo(uA.y) + bf2f_lo(uB.y);
        a3 += bf2f_hi(uA.y) + bf2f_hi(uB.y);
#endif
    }
    for (; i < e; i += 4) {
        int idx = i + g;
        bool valid = idx < e;
        int s = srcSorted[valid ? idx : i];
        uint2 u = ((const uint2*)(p + (size_t)s * 32))[lf];
        float w = valid ? 1.f : 0.f;
#if USE_FDOT2
        h2 wv = {(_Float16)w, (_Float16)0.0f};
        h2 wv2 = {(_Float16)0.0f, (_Float16)w};
        a0 = __builtin_amdgcn_fdot2(as_h2(u.x), wv, a0, false);
        a1 = __builtin_amdgcn_fdot2(as_h2(u.x), wv2, a1, false);
        a2 = __builtin_amdgcn_fdot2(as_h2(u.y), wv, a2, false);
        a3 = __builtin_amdgcn_fdot2(as_h2(u.y), wv2, a3, false);
#else
        a0 = fmaf(bf2f_lo(u.x), w, a0);
        a1 = fmaf(bf2f_hi(u.x), w, a1);
        a2 = fmaf(bf2f_lo(u.y), w, a2);
        a3 = fmaf(bf2f_hi(u.y), w, a3);
#endif
    }
    a0 += __shfl_down(a0, 32); a1 += __shfl_down(a1, 32);
    a2 += __shfl_down(a2, 32); a3 += __shfl_down(a3, 32);
    a0 += __shfl_down(a0, 16); a1 += __shfl_down(a1, 16);
    a2 += __shfl_down(a2, 16); a3 += __shfl_down(a3, 16);
    if (lane < 16) {
        float inv = 1.0f / (float)max(e - b, 1);
        f32x4 qv = ((const f32x4*)(q + (size_t)node * 64))[lf];
        f32x4 o;
        o.x = 1.0f / (1.0f + __expf(-(a0 * inv + qv.x)));
        o.y = 1.0f / (1.0f + __expf(-(a1 * inv + qv.y)));
        o.z = 1.0f / (1.0f + __expf(-(a2 * inv + qv.z)));
        o.w = 1.0f / (1.0f + __expf(-(a3 * inv + qv.w)));
        ((f32x4*)(out + (size_t)node * 64))[lf] = o;
    }
}

// ---------------- launch ----------------

extern "C" void kernel_launch(void* const* d_in, const int* in_sizes, int n_in,
                              void* d_out, int out_size, void* d_ws, size_t ws_size,
                              hipStream_t stream) {
    const float* x   = (const float*)d_in[0];
    const int*   ei  = (const int*)d_in[1];
    const float* Wl1 = (const float*)d_in[2];
    const float* bl1 = (const float*)d_in[3];
    const float* Wr1 = (const float*)d_in[4];
    const float* Wl2 = (const float*)d_in[5];
    const float* bl2 = (const float*)d_in[6];
    const float* Wr2 = (const float*)d_in[7];
    float* out = (float*)d_out;

    const int* src = ei;
    const int* dst = ei + N_EDGES;

    char* ws = (char*)d_ws;
    size_t off = 0;
    auto carve = [&](size_t bytes) -> void* {
        void* ptr = ws + off;
        off = (off + bytes + 255) & ~(size_t)255;
        return ptr;
    };
    int* rowStart     = (int*)carve((N_NODES + 1) * sizeof(int));
    int* bucketCursor = (int*)carve(NB_BUCKETS * sizeof(int));
    unsigned* bucketData = (unsigned*)carve((size_t)NB_BUCKETS * BUCKET_CAP * sizeof(unsigned));
    int* srcSorted    = (int*)carve(N_EDGES * sizeof(int));
    unsigned* xb      = (unsigned*)carve((size_t)N_NODES * 64 * sizeof(unsigned));   // bf16 x
    unsigned* xq      = (unsigned*)carve((size_t)N_NODES * 32 * sizeof(unsigned));   // fp8 x
    unsigned* meanb   = (unsigned*)carve((size_t)N_NODES * 64 * sizeof(unsigned));
    unsigned short* p = (unsigned short*)carve((size_t)N_NODES * 64 * sizeof(short)); // fp16/bf16
    unsigned short* B1 = (unsigned short*)carve(256 * 128 * sizeof(short));
    unsigned short* B2 = (unsigned short*)carve(128 * 128 * sizeof(short));
    float* q = (float*)xb;   // overlay: q[row] replaces xb[row] after that wave's xb prefetch

    // K1: fused setup
    hipMemsetAsync(bucketCursor, 0, NB_BUCKETS * sizeof(int), stream);
    setup_fused<<<NBLK_SCATTER + NBLK_CONVERT + NBLK_PREPB, 256, 0, stream>>>(
        src, dst, bucketCursor, bucketData, x, xb, xq, Wl1, Wr1, Wl2, Wr2, B1, B2);

    // K2: CSR
    bucket_to_csr<<<NB_BUCKETS, 256, 0, stream>>>(bucketData, bucketCursor, rowStart, srcSorted);

    // K3: layer-1 aggregation
    agg1_kernel<<<(N_NODES + 3) / 4, 256, 0, stream>>>(xq, rowStart, srcSorted, meanb);

    // K4: fused GEMMs (32 KB B ping-buffer, h in LDS)
    gemm12_kernel<<<(N_NODES + 127) / 128, 512, 0, stream>>>(
        (const unsigned short*)meanb, (const unsigned short*)xb, B1, B2, bl1, bl2, p, q);

    // K5: layer-2 aggregation + sigmoid
    agg2_kernel<<<(N_NODES + 3) / 4, 256, 0, stream>>>((const unsigned*)p, q,
                                                       rowStart, srcSorted, out);
}